// Round 1
// baseline (12856.889 us; speedup 1.0000x reference)
//
#include <hip/hip_runtime.h>

typedef unsigned short u16;
typedef __bf16 bf16x8 __attribute__((ext_vector_type(8)));
typedef float f32x4 __attribute__((ext_vector_type(4)));

#define AS1 __attribute__((address_space(1)))
#define AS3 __attribute__((address_space(3)))

// B=256, A=5, T=64, NIN=4, NHID=256, L=2, H=1280, 4H=5120, steps=63

__device__ __forceinline__ u16 f2bf(float f) {
    union { float f; unsigned int u; } v; v.f = f;
    unsigned int r = v.u + 0x7fffu + ((v.u >> 16) & 1u);
    return (u16)(r >> 16);
}

__device__ __forceinline__ void ld_lds16(const u16* g, u16* l) {
    __builtin_amdgcn_global_load_lds((AS1 unsigned int*)(unsigned long long)(const void*)g,
                                     (AS3 unsigned int*)l, 16, 0, 0);
}

__device__ __forceinline__ float sigm(float x) { return 1.f / (1.f + __expf(-x)); }
__device__ __forceinline__ float tanh_f(float x) { return 1.f - 2.f / (__expf(2.f * x) + 1.f); }

// ---------------------------------------------------------------------------
// Weight-prep kernels (unchanged)
// ---------------------------------------------------------------------------
__global__ __launch_bounds__(256) void cvt_kernel(const float* __restrict__ src,
                                                  u16* __restrict__ dst, int n) {
    int i = (blockIdx.x * 256 + threadIdx.x) * 4;
    if (i >= n) return;
    float4 v = *(const float4*)(src + i);
    ushort4 o;
    o.x = f2bf(v.x); o.y = f2bf(v.y); o.z = f2bf(v.z); o.w = f2bf(v.w);
    *(ushort4*)(dst + i) = o;
}

__global__ __launch_bounds__(256) void cvt_wcat(const float* __restrict__ wih,
                                                const float* __restrict__ whh,
                                                u16* __restrict__ dst) {
    long long idx = ((long long)blockIdx.x * 256 + threadIdx.x) * 4;
    int k = (int)(idx % 2560);
    long long rr = idx / 2560;
    int l = (int)(rr / 5120), r = (int)(rr % 5120);
    int j = r >> 2, g = r & 3;
    long long srow = (long long)l * 5120 + g * 1280 + j;
    const float* s = (k < 1280) ? (wih + srow * 1280 + k) : (whh + srow * 1280 + (k - 1280));
    float4 v = *(const float4*)s;
    ushort4 o;
    o.x = f2bf(v.x); o.y = f2bf(v.y); o.z = f2bf(v.z); o.w = f2bf(v.w);
    *(ushort4*)(dst + idx) = o;
}

__global__ __launch_bounds__(256) void cvt_w12p(const float* __restrict__ w,
                                                unsigned int* __restrict__ dst) {
    int idx = blockIdx.x * 256 + threadIdx.x;  // 32768
    int kk = idx >> 8, j = idx & 255;
    float f0 = w[j * 256 + 2 * kk], f1 = w[j * 256 + 2 * kk + 1];
    dst[idx] = (unsigned)f2bf(f0) | ((unsigned)f2bf(f1) << 16);
}

// ---------------------------------------------------------------------------
// core64: 64x128 tile, K=1280 (20 iters), triple-buffered prefetch (depth 2)
// ---------------------------------------------------------------------------
__device__ __forceinline__ void core64(
    const u16* A, int lda, const u16* Bw, int ldb,
    int m0, int n0, u16* As, u16* Bs, f32x4 (&acc)[2][4]) {
    const int nIter = 20;
    int tid = threadIdx.x;
    int w = tid >> 6, l = tid & 63;
    int r8 = l >> 3, g8 = (l & 7) ^ r8;
    const u16* aP = A + (size_t)(m0 + w * 8 + r8) * lda + g8 * 8;
    const u16* bP = Bw + (size_t)(n0 + w * 8 + r8) * ldb + g8 * 8;
    u16* aD = As + w * 512;
    u16* bD = Bs + w * 512;

#define ISSUE64(it)                                            \
    {                                                          \
        int bsel = (it) % 3;                                   \
        const u16* ap = aP + (it) * 64;                        \
        const u16* bp = bP + (it) * 64;                        \
        u16* ad = aD + bsel * 4096;                            \
        u16* bd = bD + bsel * 8192;                            \
        ld_lds16(ap, ad);                                      \
        ld_lds16(ap + (size_t)32 * lda, ad + 2048);            \
        ld_lds16(bp, bd);                                      \
        ld_lds16(bp + (size_t)32 * ldb, bd + 2048);            \
        ld_lds16(bp + (size_t)64 * ldb, bd + 4096);            \
        ld_lds16(bp + (size_t)96 * ldb, bd + 6144);            \
    }

    ISSUE64(0);
    ISSUE64(1);
    int wm = w >> 1, wn = w & 1, q = l >> 4, m16 = l & 15;
    for (int it = 0; it < nIter; ++it) {
        if (it + 2 < nIter) ISSUE64(it + 2);
        int ahead = nIter - 1 - it; if (ahead > 2) ahead = 2;
        if (ahead == 2) asm volatile("s_waitcnt vmcnt(12)" ::: "memory");
        else if (ahead == 1) asm volatile("s_waitcnt vmcnt(6)" ::: "memory");
        else asm volatile("s_waitcnt vmcnt(0)" ::: "memory");
        asm volatile("s_barrier" ::: "memory");
        const u16* as = As + (it % 3) * 4096;
        const u16* bs = Bs + (it % 3) * 8192;
#pragma unroll
        for (int ks = 0; ks < 2; ks++) {
            bf16x8 af[2], bfr[4];
            int gsw = (ks * 4 + q) ^ (m16 & 7);
#pragma unroll
            for (int i = 0; i < 2; i++) {
                int m = wm * 32 + i * 16 + m16;
                af[i] = *(const bf16x8*)&as[m * 64 + gsw * 8];
            }
#pragma unroll
            for (int j = 0; j < 4; j++) {
                int n = wn * 64 + j * 16 + m16;
                bfr[j] = *(const bf16x8*)&bs[n * 64 + gsw * 8];
            }
#pragma unroll
            for (int i = 0; i < 2; i++)
#pragma unroll
                for (int j = 0; j < 4; j++)
                    acc[i][j] = __builtin_amdgcn_mfma_f32_16x16x32_bf16(af[i], bfr[j], acc[i][j], 0, 0, 0);
        }
        asm volatile("s_barrier" ::: "memory");
    }
#undef ISSUE64
}

// ---------------------------------------------------------------------------
// core128: 128x128 tile, K=1280 (20 iters), triple-buffered
// ---------------------------------------------------------------------------
__device__ __forceinline__ void core128(
    const u16* A, int lda, const u16* Bw, int ldb,
    int m0, int n0, u16* As, u16* Bs, f32x4 (&acc)[4][4]) {
    const int nIter = 20;
    int tid = threadIdx.x;
    int w = tid >> 6, l = tid & 63;
    int r8 = l >> 3, g8 = (l & 7) ^ r8;
    const u16* aP = A + (size_t)(m0 + w * 32 + r8) * lda + g8 * 8;
    const u16* bP = Bw + (size_t)(n0 + w * 32 + r8) * ldb + g8 * 8;
    u16* aD = As + w * 2048;
    u16* bD = Bs + w * 2048;

#define ISSUE128(it)                                           \
    {                                                          \
        int bsel = (it) % 3;                                   \
        const u16* ap = aP + (it) * 64;                        \
        const u16* bp = bP + (it) * 64;                        \
        u16* ad = aD + bsel * 8192;                            \
        u16* bd = bD + bsel * 8192;                            \
        ld_lds16(ap, ad);                                      \
        ld_lds16(ap + (size_t)8 * lda, ad + 512);              \
        ld_lds16(ap + (size_t)16 * lda, ad + 1024);            \
        ld_lds16(ap + (size_t)24 * lda, ad + 1536);            \
        ld_lds16(bp, bd);                                      \
        ld_lds16(bp + (size_t)8 * ldb, bd + 512);              \
        ld_lds16(bp + (size_t)16 * ldb, bd + 1024);            \
        ld_lds16(bp + (size_t)24 * ldb, bd + 1536);            \
    }

    ISSUE128(0);
    ISSUE128(1);
    int wm = w >> 1, wn = w & 1, q = l >> 4, m16 = l & 15;
    for (int it = 0; it < nIter; ++it) {
        if (it + 2 < nIter) ISSUE128(it + 2);
        int ahead = nIter - 1 - it; if (ahead > 2) ahead = 2;
        if (ahead == 2) asm volatile("s_waitcnt vmcnt(16)" ::: "memory");
        else if (ahead == 1) asm volatile("s_waitcnt vmcnt(8)" ::: "memory");
        else asm volatile("s_waitcnt vmcnt(0)" ::: "memory");
        asm volatile("s_barrier" ::: "memory");
        const u16* as = As + (it % 3) * 8192;
        const u16* bs = Bs + (it % 3) * 8192;
#pragma unroll
        for (int ks = 0; ks < 2; ks++) {
            bf16x8 af[4], bfr[4];
            int gsw = (ks * 4 + q) ^ (m16 & 7);
#pragma unroll
            for (int i = 0; i < 4; i++) {
                int m = wm * 64 + i * 16 + m16;
                af[i] = *(const bf16x8*)&as[m * 64 + gsw * 8];
            }
#pragma unroll
            for (int j = 0; j < 4; j++) {
                int n = wn * 64 + j * 16 + m16;
                bfr[j] = *(const bf16x8*)&bs[n * 64 + gsw * 8];
            }
#pragma unroll
            for (int i = 0; i < 4; i++)
#pragma unroll
                for (int j = 0; j < 4; j++)
                    acc[i][j] = __builtin_amdgcn_mfma_f32_16x16x32_bf16(af[i], bfr[j], acc[i][j], 0, 0, 0);
        }
        asm volatile("s_barrier" ::: "memory");
    }
#undef ISSUE128
}

// ---------------------------------------------------------------------------
// Grid barrier: monotonic-epoch arrive counter + release flag (separate line).
// __threadfence on both sides handles cross-XCD L2 writeback/invalidate.
// __syncthreads drains vmcnt, so cores' counted-vmcnt logic restarts clean.
// ---------------------------------------------------------------------------
__device__ __forceinline__ void grid_sync(unsigned* bar, unsigned ep) {
    __syncthreads();
    if (threadIdx.x == 0) {
        __threadfence();
        unsigned old = atomicAdd(&bar[0], 1u);
        if (old == ep * 256u + 255u) {
            __hip_atomic_store(&bar[32], ep + 1u, __ATOMIC_RELEASE, __HIP_MEMORY_SCOPE_AGENT);
        } else {
            while (__hip_atomic_load(&bar[32], __ATOMIC_RELAXED, __HIP_MEMORY_SCOPE_AGENT) < ep + 1u)
                __builtin_amdgcn_s_sleep(8);
        }
    }
    __syncthreads();
    __threadfence();
}

// ---------------------------------------------------------------------------
// Phase bodies (from the proven k_gates / k_c / k_out kernels)
// ---------------------------------------------------------------------------
__device__ __forceinline__ void do_gates(
    int task, const u16* __restrict__ A, const u16* __restrict__ Bw,
    const float* __restrict__ ghh, const float* __restrict__ bih,
    const float* __restrict__ bhh, float (&creg)[8], u16* __restrict__ hout,
    char* smem) {
    u16* As = (u16*)smem;
    u16* Bs = (u16*)(smem + 24576);
    float (*cb)[132] = (float(*)[132])smem;   // overlay after core

    int nb = task % 40, mb = task / 40;
    int n0 = nb * 128, m0 = mb * 64;

    f32x4 acc[2][4];
#pragma unroll
    for (int i = 0; i < 2; i++)
#pragma unroll
        for (int j = 0; j < 4; j++) acc[i][j] = (f32x4){0.f, 0.f, 0.f, 0.f};

    core64(A, 1280, Bw, 2560, m0, n0, As, Bs, acc);

    int tid = threadIdx.x;
    int w = tid >> 6, l = tid & 63;
    int wm = w >> 1, wn = w & 1, q = l >> 4, m16 = l & 15;
#pragma unroll
    for (int i = 0; i < 2; i++)
#pragma unroll
        for (int j = 0; j < 4; j++)
#pragma unroll
            for (int r = 0; r < 4; r++) {
                int rl = wm * 32 + i * 16 + q * 4 + r;
                int cl = wn * 64 + j * 16 + m16;
                cb[rl][cl] = acc[i][j][r] + ghh[(size_t)(m0 + rl) * 5120 + n0 + cl];
            }
    __syncthreads();

    int jt = tid & 31, bt0 = tid >> 5;
    int jg = (n0 >> 2) + jt;
    float bI = bih[jg] + bhh[jg];
    float bF = bih[1280 + jg] + bhh[1280 + jg];
    float bG = bih[2560 + jg] + bhh[2560 + jg];
    float bO = bih[3840 + jg] + bhh[3840 + jg];
#pragma unroll
    for (int p = 0; p < 8; p++) {
        int bt = bt0 + p * 8;
        float4 g4 = *(const float4*)&cb[bt][jt * 4];   // i,f,g,o
        int b = m0 + bt;
        float cv = creg[p];                             // register-resident cell state
        float cn = sigm(g4.y + bF) * cv + sigm(g4.x + bI) * tanh_f(g4.z + bG);
        creg[p] = cn;
        hout[(size_t)b * 1280 + jg] = f2bf(sigm(g4.w + bO) * tanh_f(cn));
    }
}

__device__ __forceinline__ void do_ghh(int task, const u16* __restrict__ Aop,
                                       const u16* __restrict__ Bop,
                                       float* __restrict__ G, char* smem) {
    u16* As = (u16*)smem;
    u16* Bs = (u16*)(smem + 49152);
    int mb = task / 40, nb = task % 40;
    int m0 = mb * 128, n0 = nb * 128;
    f32x4 acc[4][4];
#pragma unroll
    for (int i = 0; i < 4; i++)
#pragma unroll
        for (int j = 0; j < 4; j++) acc[i][j] = (f32x4){0.f, 0.f, 0.f, 0.f};
    core128(Aop, 1280, Bop, 2560, m0, n0, As, Bs, acc);
    int tid = threadIdx.x;
    int w = tid >> 6, l = tid & 63;
    int wm = w >> 1, wn = w & 1, q = l >> 4, m16 = l & 15;
#pragma unroll
    for (int i = 0; i < 4; i++) {
        int row = m0 + wm * 64 + i * 16 + q * 4;
#pragma unroll
        for (int j = 0; j < 4; j++) {
            int col = n0 + wn * 64 + j * 16 + m16;
#pragma unroll
            for (int r = 0; r < 4; r++)
                G[(size_t)(row + r) * 5120 + col] = acc[i][j][r];
        }
    }
}

__device__ __forceinline__ void do_y(int task, const u16* __restrict__ h1,
                                     const u16* __restrict__ w21,
                                     const float* __restrict__ b21,
                                     float* __restrict__ yb, char* smem) {
    u16* As = (u16*)smem;
    u16* Bs = (u16*)(smem + 24576);
    int nb = task % 10, mb = task / 10;
    int n0 = nb * 128, m0 = mb * 64;
    f32x4 acc[2][4];
#pragma unroll
    for (int i = 0; i < 2; i++)
#pragma unroll
        for (int j = 0; j < 4; j++) acc[i][j] = (f32x4){0.f, 0.f, 0.f, 0.f};
    core64(h1, 1280, w21, 1280, m0, n0, As, Bs, acc);
    int tid = threadIdx.x;
    int w = tid >> 6, l = tid & 63;
    int wm = w >> 1, wn = w & 1, q = l >> 4, m16 = l & 15;
#pragma unroll
    for (int i = 0; i < 2; i++) {
        int row = m0 + wm * 32 + i * 16 + q * 4;
#pragma unroll
        for (int j = 0; j < 4; j++) {
            int col = n0 + wn * 64 + j * 16 + m16;
#pragma unroll
            for (int r = 0; r < 4; r++)
                yb[(size_t)(row + r) * 1280 + col] = fmaxf(acc[i][j][r] + b21[col], 0.f);
        }
    }
}

__device__ __forceinline__ void do_head(bool first, int t, int b,
    const float* __restrict__ yb, const float* __restrict__ w22,
    const float* __restrict__ b22, const float* __restrict__ inputs,
    const int* __restrict__ ps, const float* __restrict__ w11,
    const float* __restrict__ b11, const unsigned int* __restrict__ w12p,
    const float* __restrict__ b12, float* __restrict__ out,
    float* __restrict__ ins_buf, u16* __restrict__ xnext, char* smem) {
    float* ins_s = (float*)smem;           // 20 floats
    float* redm = (float*)(smem + 128);    // [4][20]
    float* act1 = (float*)(smem + 512);    // 1280 floats
    int tid = threadIdx.x;
    int w = tid >> 6, l = tid & 63;
    int psv = ps[0];

    if (!first) {
        float acc[20];
#pragma unroll
        for (int j = 0; j < 20; j++) acc[j] = 0.f;
        const float* yrow = yb + (size_t)b * 1280;
#pragma unroll
        for (int s = 0; s < 5; s++) {
            int k = w * 320 + s * 64 + l;
            float yv = yrow[k];
#pragma unroll
            for (int j = 0; j < 20; j++) acc[j] = fmaf(yv, w22[j * 1280 + k], acc[j]);
        }
#pragma unroll
        for (int j = 0; j < 20; j++)
#pragma unroll
            for (int off = 32; off; off >>= 1) acc[j] += __shfl_xor(acc[j], off);
        if (l < 20) redm[w * 20 + l] = acc[l];
        __syncthreads();
        if (tid < 20) {
            float o = redm[tid] + redm[20 + tid] + redm[40 + tid] + redm[60 + tid]
                      + b22[tid] + ins_buf[b * 20 + tid];
            int a = tid >> 2, n = tid & 3;
            out[(((size_t)b * 5 + a) * 63 + t) * 4 + n] = o;
            float nx = (((t + 1) % psv) == 0)
                           ? inputs[(((size_t)b * 5 + a) * 64 + (t + 1)) * 4 + n] : o;
            ins_s[tid] = nx;
            ins_buf[b * 20 + tid] = nx;
        }
    } else {
        if (tid < 20) {
            int a = tid >> 2, n = tid & 3;
            float nx = inputs[(((size_t)b * 5 + a) * 64) * 4 + n];
            ins_s[tid] = nx;
            ins_buf[b * 20 + tid] = nx;
        }
    }
    __syncthreads();

    int j = tid;
    float4 wv = *(const float4*)(w11 + j * 4);
    float bb = b11[j];
#pragma unroll
    for (int g = 0; g < 5; g++) {
        float v = fmaf(wv.x, ins_s[g * 4],
                  fmaf(wv.y, ins_s[g * 4 + 1],
                  fmaf(wv.z, ins_s[g * 4 + 2],
                  fmaf(wv.w, ins_s[g * 4 + 3], bb))));
        act1[g * 256 + j] = fmaxf(v, 0.f);
    }
    __syncthreads();

    float acc2[5];
    float bb2 = b12[j];
#pragma unroll
    for (int g = 0; g < 5; g++) acc2[g] = bb2;
    for (int kk = 0; kk < 128; kk++) {
        unsigned int pr = w12p[kk * 256 + j];
        union { unsigned int u; float f; } lo, hi;
        lo.u = pr << 16; hi.u = pr & 0xffff0000u;
#pragma unroll
        for (int g = 0; g < 5; g++)
            acc2[g] = fmaf(lo.f, act1[g * 256 + 2 * kk],
                      fmaf(hi.f, act1[g * 256 + 2 * kk + 1], acc2[g]));
    }
#pragma unroll
    for (int g = 0; g < 5; g++)
        xnext[(size_t)b * 1280 + g * 256 + j] = f2bf(fmaxf(acc2[g], 0.f));
}

// ---------------------------------------------------------------------------
// Persistent kernel: 256 blocks (1/CU, forced by 96KB LDS), all 63 steps.
// ph1: gates0 (0..159) || ghh1' = h1(t-1)@whh1 (160..239)
// ph2: gates1 (0..159) || ghh0' = h0@whh0     (160..239)
// ph3: y = relu(h1@w21) (0..39)
// ph4: head/out/MLP -> x(t+1) (all 256)
// ---------------------------------------------------------------------------
__global__ __launch_bounds__(256, 1) void k_persist(
    const u16* __restrict__ wcat, const u16* __restrict__ w21,
    const unsigned int* __restrict__ w12p,
    const float* __restrict__ inputs, const int* __restrict__ ps,
    const float* __restrict__ w11, const float* __restrict__ b11,
    const float* __restrict__ b12,
    const float* __restrict__ bih, const float* __restrict__ bhh,
    const float* __restrict__ b21,
    const float* __restrict__ w22, const float* __restrict__ b22,
    float* __restrict__ out,
    u16* __restrict__ xbf, u16* __restrict__ h0, u16* __restrict__ h1,
    float* __restrict__ ghh0, float* __restrict__ ghh1,
    float* __restrict__ yb, float* __restrict__ ins_b,
    unsigned* __restrict__ bar) {
    __shared__ __align__(16) char smem[98304];
    int bid = blockIdx.x;
    unsigned ep = 0;
    float creg0[8], creg1[8];   // register-resident LSTM cell state (c=0 init)
#pragma unroll
    for (int p = 0; p < 8; p++) { creg0[p] = 0.f; creg1[p] = 0.f; }

    // phase 0: t=-1 head -> ins(0), x(0)
    do_head(true, -1, bid, yb, w22, b22, inputs, ps, w11, b11, w12p, b12,
            out, ins_b, xbf, smem);
    grid_sync(bar, ep); ep++;

    for (int t = 0; t < 63; ++t) {
        // ph1
        if (bid < 160)
            do_gates(bid, xbf, wcat, ghh0, bih, bhh, creg0, h0, smem);
        else if (bid < 240)
            do_ghh(bid - 160, h1, wcat + 13107200 + 1280, ghh1, smem);
        grid_sync(bar, ep); ep++;

        // ph2
        if (bid < 160)
            do_gates(bid, h0, wcat + 13107200, ghh1, bih + 5120, bhh + 5120,
                     creg1, h1, smem);
        else if (bid < 240)
            do_ghh(bid - 160, h0, wcat + 1280, ghh0, smem);
        grid_sync(bar, ep); ep++;

        // ph3
        if (bid < 40)
            do_y(bid, h1, w21, b21, yb, smem);
        grid_sync(bar, ep); ep++;

        // ph4
        do_head(false, t, bid, yb, w22, b22, inputs, ps, w11, b11, w12p, b12,
                out, ins_b, xbf, smem);
        grid_sync(bar, ep); ep++;
    }
}

// ---------------------------------------------------------------------------
extern "C" void kernel_launch(void* const* d_in, const int* in_sizes, int n_in,
                              void* d_out, int out_size, void* d_ws, size_t ws_size,
                              hipStream_t stream) {
    const float* inputs = (const float*)d_in[0];
    const float* w1_1 = (const float*)d_in[1];
    const float* b1_1 = (const float*)d_in[2];
    const float* w1_2 = (const float*)d_in[3];
    const float* b1_2 = (const float*)d_in[4];
    const float* w_ih = (const float*)d_in[5];
    const float* w_hh = (const float*)d_in[6];
    const float* b_ih = (const float*)d_in[7];
    const float* b_hh = (const float*)d_in[8];
    const float* w2_1 = (const float*)d_in[9];
    const float* b2_1 = (const float*)d_in[10];
    const float* w2_2 = (const float*)d_in[11];
    const float* b2_2 = (const float*)d_in[12];
    const int* ps = (const int*)d_in[13];
    float* out = (float*)d_out;

    char* ws = (char*)d_ws;
    size_t off = 0;
    auto alloc = [&](size_t bytes) -> void* {
        void* p = ws + off;
        off = (off + bytes + 255) & ~(size_t)255;
        return p;
    };
    u16* wcat = (u16*)alloc(26214400ull * 2);        // [2][5120][2560]
    u16* w21_bf = (u16*)alloc(1638400ull * 2);       // [1280][1280]
    unsigned int* w12p = (unsigned int*)alloc(32768ull * 4);
    u16* xbf = (u16*)alloc(327680ull * 2);           // [256][1280]
    u16* h0 = (u16*)alloc(327680ull * 2);            // [256][1280]
    u16* h1 = (u16*)alloc(327680ull * 2);            // [256][1280]
    float* ghh0 = (float*)alloc(1310720ull * 4);     // [256][5120]
    float* ghh1 = (float*)alloc(1310720ull * 4);
    float* yb = (float*)alloc(327680ull * 4);        // [256][1280]
    float* ins_b = (float*)alloc(5120ull * 4);       // [256][20]
    unsigned* bar = (unsigned*)alloc(256ull * 4);    // barrier state

    // weight prep + state init
    cvt_wcat<<<25600, 256, 0, stream>>>(w_ih, w_hh, wcat);
    cvt_kernel<<<1600, 256, 0, stream>>>(w2_1, w21_bf, 1638400);
    cvt_w12p<<<128, 256, 0, stream>>>(w1_2, w12p);
    hipMemsetAsync(ghh0, 0, 1310720ull * 4, stream);   // h0(-1)=0 -> ghh0=0
    hipMemsetAsync(h1, 0, 327680ull * 2, stream);      // h1(-1)=0 (ghh1 computed in ph1 t=0)
    hipMemsetAsync(bar, 0, 256ull * 4, stream);

    k_persist<<<256, 256, 0, stream>>>(wcat, w21_bf, w12p, inputs, ps,
                                       w1_1, b1_1, b1_2, b_ih, b_hh, b2_1,
                                       w2_2, b2_2, out, xbf, h0, h1,
                                       ghh0, ghh1, yb, ins_b, bar);
}

// Round 2
// 12762.498 us; speedup vs baseline: 1.0074x; 1.0074x over previous
//
#include <hip/hip_runtime.h>

typedef unsigned short u16;
typedef __bf16 bf16x8 __attribute__((ext_vector_type(8)));
typedef float f32x4 __attribute__((ext_vector_type(4)));

#define AS1 __attribute__((address_space(1)))
#define AS3 __attribute__((address_space(3)))

// B=256, A=5, T=64, NIN=4, NHID=256, L=2, H=1280, 4H=5120, steps=63

__device__ __forceinline__ u16 f2bf(float f) {
    union { float f; unsigned int u; } v; v.f = f;
    unsigned int r = v.u + 0x7fffu + ((v.u >> 16) & 1u);
    return (u16)(r >> 16);
}

__device__ __forceinline__ void ld_lds16(const u16* g, u16* l) {
    __builtin_amdgcn_global_load_lds((AS1 unsigned int*)(unsigned long long)(const void*)g,
                                     (AS3 unsigned int*)l, 16, 0, 0);
}

__device__ __forceinline__ float sigm(float x) { return 1.f / (1.f + __expf(-x)); }
__device__ __forceinline__ float tanh_f(float x) { return 1.f - 2.f / (__expf(2.f * x) + 1.f); }

// ---------------------------------------------------------------------------
// Weight-prep kernels (unchanged)
// ---------------------------------------------------------------------------
__global__ __launch_bounds__(256) void cvt_kernel(const float* __restrict__ src,
                                                  u16* __restrict__ dst, int n) {
    int i = (blockIdx.x * 256 + threadIdx.x) * 4;
    if (i >= n) return;
    float4 v = *(const float4*)(src + i);
    ushort4 o;
    o.x = f2bf(v.x); o.y = f2bf(v.y); o.z = f2bf(v.z); o.w = f2bf(v.w);
    *(ushort4*)(dst + i) = o;
}

__global__ __launch_bounds__(256) void cvt_wcat(const float* __restrict__ wih,
                                                const float* __restrict__ whh,
                                                u16* __restrict__ dst) {
    long long idx = ((long long)blockIdx.x * 256 + threadIdx.x) * 4;
    int k = (int)(idx % 2560);
    long long rr = idx / 2560;
    int l = (int)(rr / 5120), r = (int)(rr % 5120);
    int j = r >> 2, g = r & 3;
    long long srow = (long long)l * 5120 + g * 1280 + j;
    const float* s = (k < 1280) ? (wih + srow * 1280 + k) : (whh + srow * 1280 + (k - 1280));
    float4 v = *(const float4*)s;
    ushort4 o;
    o.x = f2bf(v.x); o.y = f2bf(v.y); o.z = f2bf(v.z); o.w = f2bf(v.w);
    *(ushort4*)(dst + idx) = o;
}

__global__ __launch_bounds__(256) void cvt_w12p(const float* __restrict__ w,
                                                unsigned int* __restrict__ dst) {
    int idx = blockIdx.x * 256 + threadIdx.x;  // 32768
    int kk = idx >> 8, j = idx & 255;
    float f0 = w[j * 256 + 2 * kk], f1 = w[j * 256 + 2 * kk + 1];
    dst[idx] = (unsigned)f2bf(f0) | ((unsigned)f2bf(f1) << 16);
}

// ---------------------------------------------------------------------------
// core64: 64x128 tile, K=1280 (20 iters), QUAD-buffered prefetch (depth 3).
// As: 4 x 4096 u16 (32KB) at smem+0, Bs: 4 x 8192 u16 (64KB) at smem+32768.
// ---------------------------------------------------------------------------
__device__ __forceinline__ void core64(
    const u16* A, int lda, const u16* Bw, int ldb,
    int m0, int n0, u16* As, u16* Bs, f32x4 (&acc)[2][4]) {
    const int nIter = 20;
    int tid = threadIdx.x;
    int w = tid >> 6, l = tid & 63;
    int r8 = l >> 3, g8 = (l & 7) ^ r8;
    const u16* aP = A + (size_t)(m0 + w * 8 + r8) * lda + g8 * 8;
    const u16* bP = Bw + (size_t)(n0 + w * 8 + r8) * ldb + g8 * 8;
    u16* aD = As + w * 512;
    u16* bD = Bs + w * 512;

#define ISSUE64(it)                                            \
    {                                                          \
        int bsel = (it) & 3;                                   \
        const u16* ap = aP + (it) * 64;                        \
        const u16* bp = bP + (it) * 64;                        \
        u16* ad = aD + bsel * 4096;                            \
        u16* bd = bD + bsel * 8192;                            \
        ld_lds16(ap, ad);                                      \
        ld_lds16(ap + (size_t)32 * lda, ad + 2048);            \
        ld_lds16(bp, bd);                                      \
        ld_lds16(bp + (size_t)32 * ldb, bd + 2048);            \
        ld_lds16(bp + (size_t)64 * ldb, bd + 4096);            \
        ld_lds16(bp + (size_t)96 * ldb, bd + 6144);            \
    }

    ISSUE64(0);
    ISSUE64(1);
    ISSUE64(2);
    int wm = w >> 1, wn = w & 1, q = l >> 4, m16 = l & 15;
    for (int it = 0; it < nIter; ++it) {
        if (it + 3 < nIter) ISSUE64(it + 3);
        int ahead = nIter - 1 - it; if (ahead > 3) ahead = 3;
        if (ahead == 3) asm volatile("s_waitcnt vmcnt(18)" ::: "memory");
        else if (ahead == 2) asm volatile("s_waitcnt vmcnt(12)" ::: "memory");
        else if (ahead == 1) asm volatile("s_waitcnt vmcnt(6)" ::: "memory");
        else asm volatile("s_waitcnt vmcnt(0)" ::: "memory");
        asm volatile("s_barrier" ::: "memory");
        const u16* as = As + (it & 3) * 4096;
        const u16* bs = Bs + (it & 3) * 8192;
#pragma unroll
        for (int ks = 0; ks < 2; ks++) {
            bf16x8 af[2], bfr[4];
            int gsw = (ks * 4 + q) ^ (m16 & 7);
#pragma unroll
            for (int i = 0; i < 2; i++) {
                int m = wm * 32 + i * 16 + m16;
                af[i] = *(const bf16x8*)&as[m * 64 + gsw * 8];
            }
#pragma unroll
            for (int j = 0; j < 4; j++) {
                int n = wn * 64 + j * 16 + m16;
                bfr[j] = *(const bf16x8*)&bs[n * 64 + gsw * 8];
            }
#pragma unroll
            for (int i = 0; i < 2; i++)
#pragma unroll
                for (int j = 0; j < 4; j++)
                    acc[i][j] = __builtin_amdgcn_mfma_f32_16x16x32_bf16(af[i], bfr[j], acc[i][j], 0, 0, 0);
        }
        asm volatile("s_barrier" ::: "memory");
    }
#undef ISSUE64
}

// ---------------------------------------------------------------------------
// core128: 128x128 tile, K=1280 (20 iters), triple-buffered (depth 2)
// As: 3 x 8192 u16 at smem+0, Bs: 3 x 8192 u16 at smem+49152.
// ---------------------------------------------------------------------------
__device__ __forceinline__ void core128(
    const u16* A, int lda, const u16* Bw, int ldb,
    int m0, int n0, u16* As, u16* Bs, f32x4 (&acc)[4][4]) {
    const int nIter = 20;
    int tid = threadIdx.x;
    int w = tid >> 6, l = tid & 63;
    int r8 = l >> 3, g8 = (l & 7) ^ r8;
    const u16* aP = A + (size_t)(m0 + w * 32 + r8) * lda + g8 * 8;
    const u16* bP = Bw + (size_t)(n0 + w * 32 + r8) * ldb + g8 * 8;
    u16* aD = As + w * 2048;
    u16* bD = Bs + w * 2048;

#define ISSUE128(it)                                           \
    {                                                          \
        int bsel = (it) % 3;                                   \
        const u16* ap = aP + (it) * 64;                        \
        const u16* bp = bP + (it) * 64;                        \
        u16* ad = aD + bsel * 8192;                            \
        u16* bd = bD + bsel * 8192;                            \
        ld_lds16(ap, ad);                                      \
        ld_lds16(ap + (size_t)8 * lda, ad + 512);              \
        ld_lds16(ap + (size_t)16 * lda, ad + 1024);            \
        ld_lds16(ap + (size_t)24 * lda, ad + 1536);            \
        ld_lds16(bp, bd);                                      \
        ld_lds16(bp + (size_t)8 * ldb, bd + 512);              \
        ld_lds16(bp + (size_t)16 * ldb, bd + 1024);            \
        ld_lds16(bp + (size_t)24 * ldb, bd + 1536);            \
    }

    ISSUE128(0);
    ISSUE128(1);
    int wm = w >> 1, wn = w & 1, q = l >> 4, m16 = l & 15;
    for (int it = 0; it < nIter; ++it) {
        if (it + 2 < nIter) ISSUE128(it + 2);
        int ahead = nIter - 1 - it; if (ahead > 2) ahead = 2;
        if (ahead == 2) asm volatile("s_waitcnt vmcnt(16)" ::: "memory");
        else if (ahead == 1) asm volatile("s_waitcnt vmcnt(8)" ::: "memory");
        else asm volatile("s_waitcnt vmcnt(0)" ::: "memory");
        asm volatile("s_barrier" ::: "memory");
        const u16* as = As + (it % 3) * 8192;
        const u16* bs = Bs + (it % 3) * 8192;
#pragma unroll
        for (int ks = 0; ks < 2; ks++) {
            bf16x8 af[4], bfr[4];
            int gsw = (ks * 4 + q) ^ (m16 & 7);
#pragma unroll
            for (int i = 0; i < 4; i++) {
                int m = wm * 64 + i * 16 + m16;
                af[i] = *(const bf16x8*)&as[m * 64 + gsw * 8];
            }
#pragma unroll
            for (int j = 0; j < 4; j++) {
                int n = wn * 64 + j * 16 + m16;
                bfr[j] = *(const bf16x8*)&bs[n * 64 + gsw * 8];
            }
#pragma unroll
            for (int i = 0; i < 4; i++)
#pragma unroll
                for (int j = 0; j < 4; j++)
                    acc[i][j] = __builtin_amdgcn_mfma_f32_16x16x32_bf16(af[i], bfr[j], acc[i][j], 0, 0, 0);
        }
        asm volatile("s_barrier" ::: "memory");
    }
#undef ISSUE128
}

// ---------------------------------------------------------------------------
// Two-level spread grid barrier.
// Layout (u32 indices, 128B lines): group counters at lines 0..7 (bid&7),
// root at line 8, release flags at lines 9..24 (bid&15).
// Arrive contention: 32/line (groups), 8 (root). Poll contention: 16/line.
// Fence semantics identical to the round-1 (correctness-verified) barrier;
// release fence skipped by blocks that wrote nothing this phase.
// ---------------------------------------------------------------------------
__device__ __forceinline__ void grid_sync(unsigned* bar, unsigned ep, bool wrote) {
    __syncthreads();
    if (threadIdx.x == 0) {
        if (wrote) __threadfence();   // push this block's stores to coherence point
        int bid = blockIdx.x;
        unsigned old = atomicAdd(&bar[(bid & 7) * 32], 1u);
        if (old == ep * 32u + 31u) {
            unsigned r = atomicAdd(&bar[8 * 32], 1u);
            if (r == ep * 8u + 7u) {
                __threadfence();
#pragma unroll
                for (int i = 0; i < 16; i++)
                    __hip_atomic_store(&bar[(9 + i) * 32], ep + 1u,
                                       __ATOMIC_RELAXED, __HIP_MEMORY_SCOPE_AGENT);
            }
        }
        volatile unsigned* fl = &bar[(9 + (bid & 15)) * 32];
        while (__hip_atomic_load((unsigned*)fl, __ATOMIC_RELAXED,
                                 __HIP_MEMORY_SCOPE_AGENT) < ep + 1u)
            __builtin_amdgcn_s_sleep(16);
    }
    __syncthreads();
    __threadfence();                  // acquire: drop stale cached lines
}

// ---------------------------------------------------------------------------
// Phase bodies
// ---------------------------------------------------------------------------
__device__ __forceinline__ void do_gates(
    int task, const u16* __restrict__ A, const u16* __restrict__ Bw,
    const float* __restrict__ ghh, const float* __restrict__ bih,
    const float* __restrict__ bhh, float (&creg)[8], u16* __restrict__ hout,
    char* smem) {
    u16* As = (u16*)smem;
    u16* Bs = (u16*)(smem + 32768);
    float (*cb)[132] = (float(*)[132])smem;   // overlay after core

    int nb = task % 40, mb = task / 40;
    int n0 = nb * 128, m0 = mb * 64;

    f32x4 acc[2][4];
#pragma unroll
    for (int i = 0; i < 2; i++)
#pragma unroll
        for (int j = 0; j < 4; j++) acc[i][j] = (f32x4){0.f, 0.f, 0.f, 0.f};

    core64(A, 1280, Bw, 2560, m0, n0, As, Bs, acc);

    int tid = threadIdx.x;
    int w = tid >> 6, l = tid & 63;
    int wm = w >> 1, wn = w & 1, q = l >> 4, m16 = l & 15;
#pragma unroll
    for (int i = 0; i < 2; i++)
#pragma unroll
        for (int j = 0; j < 4; j++)
#pragma unroll
            for (int r = 0; r < 4; r++) {
                int rl = wm * 32 + i * 16 + q * 4 + r;
                int cl = wn * 64 + j * 16 + m16;
                cb[rl][cl] = acc[i][j][r] + ghh[(size_t)(m0 + rl) * 5120 + n0 + cl];
            }
    __syncthreads();

    int jt = tid & 31, bt0 = tid >> 5;
    int jg = (n0 >> 2) + jt;
    float bI = bih[jg] + bhh[jg];
    float bF = bih[1280 + jg] + bhh[1280 + jg];
    float bG = bih[2560 + jg] + bhh[2560 + jg];
    float bO = bih[3840 + jg] + bhh[3840 + jg];
#pragma unroll
    for (int p = 0; p < 8; p++) {
        int bt = bt0 + p * 8;
        float4 g4 = *(const float4*)&cb[bt][jt * 4];   // i,f,g,o
        int b = m0 + bt;
        float cv = creg[p];                             // register-resident cell state
        float cn = sigm(g4.y + bF) * cv + sigm(g4.x + bI) * tanh_f(g4.z + bG);
        creg[p] = cn;
        hout[(size_t)b * 1280 + jg] = f2bf(sigm(g4.w + bO) * tanh_f(cn));
    }
}

__device__ __forceinline__ void do_ghh(int task, const u16* __restrict__ Aop,
                                       const u16* __restrict__ Bop,
                                       float* __restrict__ G, char* smem) {
    u16* As = (u16*)smem;
    u16* Bs = (u16*)(smem + 49152);
    int mb = task / 40, nb = task % 40;
    int m0 = mb * 128, n0 = nb * 128;
    f32x4 acc[4][4];
#pragma unroll
    for (int i = 0; i < 4; i++)
#pragma unroll
        for (int j = 0; j < 4; j++) acc[i][j] = (f32x4){0.f, 0.f, 0.f, 0.f};
    core128(Aop, 1280, Bop, 2560, m0, n0, As, Bs, acc);
    int tid = threadIdx.x;
    int w = tid >> 6, l = tid & 63;
    int wm = w >> 1, wn = w & 1, q = l >> 4, m16 = l & 15;
#pragma unroll
    for (int i = 0; i < 4; i++) {
        int row = m0 + wm * 64 + i * 16 + q * 4;
#pragma unroll
        for (int j = 0; j < 4; j++) {
            int col = n0 + wn * 64 + j * 16 + m16;
#pragma unroll
            for (int r = 0; r < 4; r++)
                G[(size_t)(row + r) * 5120 + col] = acc[i][j][r];
        }
    }
}

__device__ __forceinline__ void do_y(int task, const u16* __restrict__ h1,
                                     const u16* __restrict__ w21,
                                     const float* __restrict__ b21,
                                     float* __restrict__ yb, char* smem) {
    u16* As = (u16*)smem;
    u16* Bs = (u16*)(smem + 32768);
    int nb = task % 10, mb = task / 10;
    int n0 = nb * 128, m0 = mb * 64;
    f32x4 acc[2][4];
#pragma unroll
    for (int i = 0; i < 2; i++)
#pragma unroll
        for (int j = 0; j < 4; j++) acc[i][j] = (f32x4){0.f, 0.f, 0.f, 0.f};
    core64(h1, 1280, w21, 1280, m0, n0, As, Bs, acc);
    int tid = threadIdx.x;
    int w = tid >> 6, l = tid & 63;
    int wm = w >> 1, wn = w & 1, q = l >> 4, m16 = l & 15;
#pragma unroll
    for (int i = 0; i < 2; i++) {
        int row = m0 + wm * 32 + i * 16 + q * 4;
#pragma unroll
        for (int j = 0; j < 4; j++) {
            int col = n0 + wn * 64 + j * 16 + m16;
#pragma unroll
            for (int r = 0; r < 4; r++)
                yb[(size_t)(row + r) * 1280 + col] = fmaxf(acc[i][j][r] + b21[col], 0.f);
        }
    }
}

__device__ __forceinline__ void do_head(bool first, int t, int b,
    const float* __restrict__ yb, const float* __restrict__ w22,
    const float* __restrict__ b22, const float* __restrict__ inputs,
    const int* __restrict__ ps, const float* __restrict__ w11,
    const float* __restrict__ b11, const unsigned int* __restrict__ w12p,
    const float* __restrict__ b12, float* __restrict__ out,
    float* __restrict__ ins_buf, u16* __restrict__ xnext, char* smem) {
    float* ins_s = (float*)smem;           // 20 floats
    float* redm = (float*)(smem + 128);    // [4][20]
    float* act1 = (float*)(smem + 512);    // 1280 floats
    int tid = threadIdx.x;
    int w = tid >> 6, l = tid & 63;
    int psv = ps[0];

    if (!first) {
        float acc[20];
#pragma unroll
        for (int j = 0; j < 20; j++) acc[j] = 0.f;
        const float* yrow = yb + (size_t)b * 1280;
#pragma unroll
        for (int s = 0; s < 5; s++) {
            int k = w * 320 + s * 64 + l;
            float yv = yrow[k];
#pragma unroll
            for (int j = 0; j < 20; j++) acc[j] = fmaf(yv, w22[j * 1280 + k], acc[j]);
        }
#pragma unroll
        for (int j = 0; j < 20; j++)
#pragma unroll
            for (int off = 32; off; off >>= 1) acc[j] += __shfl_xor(acc[j], off);
        if (l < 20) redm[w * 20 + l] = acc[l];
        __syncthreads();
        if (tid < 20) {
            float o = redm[tid] + redm[20 + tid] + redm[40 + tid] + redm[60 + tid]
                      + b22[tid] + ins_buf[b * 20 + tid];
            int a = tid >> 2, n = tid & 3;
            out[(((size_t)b * 5 + a) * 63 + t) * 4 + n] = o;
            float nx = (((t + 1) % psv) == 0)
                           ? inputs[(((size_t)b * 5 + a) * 64 + (t + 1)) * 4 + n] : o;
            ins_s[tid] = nx;
            ins_buf[b * 20 + tid] = nx;
        }
    } else {
        if (tid < 20) {
            int a = tid >> 2, n = tid & 3;
            float nx = inputs[(((size_t)b * 5 + a) * 64) * 4 + n];
            ins_s[tid] = nx;
            ins_buf[b * 20 + tid] = nx;
        }
    }
    __syncthreads();

    int j = tid;
    float4 wv = *(const float4*)(w11 + j * 4);
    float bb = b11[j];
#pragma unroll
    for (int g = 0; g < 5; g++) {
        float v = fmaf(wv.x, ins_s[g * 4],
                  fmaf(wv.y, ins_s[g * 4 + 1],
                  fmaf(wv.z, ins_s[g * 4 + 2],
                  fmaf(wv.w, ins_s[g * 4 + 3], bb))));
        act1[g * 256 + j] = fmaxf(v, 0.f);
    }
    __syncthreads();

    float acc2[5];
    float bb2 = b12[j];
#pragma unroll
    for (int g = 0; g < 5; g++) acc2[g] = bb2;
    for (int kk = 0; kk < 128; kk++) {
        unsigned int pr = w12p[kk * 256 + j];
        union { unsigned int u; float f; } lo, hi;
        lo.u = pr << 16; hi.u = pr & 0xffff0000u;
#pragma unroll
        for (int g = 0; g < 5; g++)
            acc2[g] = fmaf(lo.f, act1[g * 256 + 2 * kk],
                      fmaf(hi.f, act1[g * 256 + 2 * kk + 1], acc2[g]));
    }
#pragma unroll
    for (int g = 0; g < 5; g++)
        xnext[(size_t)b * 1280 + g * 256 + j] = f2bf(fmaxf(acc2[g], 0.f));
}

// ---------------------------------------------------------------------------
// Persistent kernel: 256 blocks (1/CU), all 63 steps.
// ph1: gates0 (0..159) || ghh1' = h1(t-1)@whh1 (160..239)
// ph2: gates1 (0..159) || ghh0' = h0@whh0     (160..239)
// ph3: y = relu(h1@w21) (0..39)
// ph4: head/out/MLP -> x(t+1) (all 256)
// ---------------------------------------------------------------------------
__global__ __launch_bounds__(256, 1) void k_persist(
    const u16* __restrict__ wcat, const u16* __restrict__ w21,
    const unsigned int* __restrict__ w12p,
    const float* __restrict__ inputs, const int* __restrict__ ps,
    const float* __restrict__ w11, const float* __restrict__ b11,
    const float* __restrict__ b12,
    const float* __restrict__ bih, const float* __restrict__ bhh,
    const float* __restrict__ b21,
    const float* __restrict__ w22, const float* __restrict__ b22,
    float* __restrict__ out,
    u16* __restrict__ xbf, u16* __restrict__ h0, u16* __restrict__ h1,
    float* __restrict__ ghh0, float* __restrict__ ghh1,
    float* __restrict__ yb, float* __restrict__ ins_b,
    unsigned* __restrict__ bar) {
    __shared__ __align__(16) char smem[98304];
    int bid = blockIdx.x;
    unsigned ep = 0;
    float creg0[8], creg1[8];   // register-resident LSTM cell state (c=0 init)
#pragma unroll
    for (int p = 0; p < 8; p++) { creg0[p] = 0.f; creg1[p] = 0.f; }

    // phase 0: t=-1 head -> ins(0), x(0)
    do_head(true, -1, bid, yb, w22, b22, inputs, ps, w11, b11, w12p, b12,
            out, ins_b, xbf, smem);
    grid_sync(bar, ep, true); ep++;

    for (int t = 0; t < 63; ++t) {
        // ph1
        if (bid < 160)
            do_gates(bid, xbf, wcat, ghh0, bih, bhh, creg0, h0, smem);
        else if (bid < 240)
            do_ghh(bid - 160, h1, wcat + 13107200 + 1280, ghh1, smem);
        grid_sync(bar, ep, bid < 240); ep++;

        // ph2
        if (bid < 160)
            do_gates(bid, h0, wcat + 13107200, ghh1, bih + 5120, bhh + 5120,
                     creg1, h1, smem);
        else if (bid < 240)
            do_ghh(bid - 160, h0, wcat + 1280, ghh0, smem);
        grid_sync(bar, ep, bid < 240); ep++;

        // ph3
        if (bid < 40)
            do_y(bid, h1, w21, b21, yb, smem);
        grid_sync(bar, ep, bid < 40); ep++;

        // ph4
        do_head(false, t, bid, yb, w22, b22, inputs, ps, w11, b11, w12p, b12,
                out, ins_b, xbf, smem);
        grid_sync(bar, ep, true); ep++;
    }
}

// ---------------------------------------------------------------------------
extern "C" void kernel_launch(void* const* d_in, const int* in_sizes, int n_in,
                              void* d_out, int out_size, void* d_ws, size_t ws_size,
                              hipStream_t stream) {
    const float* inputs = (const float*)d_in[0];
    const float* w1_1 = (const float*)d_in[1];
    const float* b1_1 = (const float*)d_in[2];
    const float* w1_2 = (const float*)d_in[3];
    const float* b1_2 = (const float*)d_in[4];
    const float* w_ih = (const float*)d_in[5];
    const float* w_hh = (const float*)d_in[6];
    const float* b_ih = (const float*)d_in[7];
    const float* b_hh = (const float*)d_in[8];
    const float* w2_1 = (const float*)d_in[9];
    const float* b2_1 = (const float*)d_in[10];
    const float* w2_2 = (const float*)d_in[11];
    const float* b2_2 = (const float*)d_in[12];
    const int* ps = (const int*)d_in[13];
    float* out = (float*)d_out;

    char* ws = (char*)d_ws;
    size_t off = 0;
    auto alloc = [&](size_t bytes) -> void* {
        void* p = ws + off;
        off = (off + bytes + 255) & ~(size_t)255;
        return p;
    };
    u16* wcat = (u16*)alloc(26214400ull * 2);        // [2][5120][2560]
    u16* w21_bf = (u16*)alloc(1638400ull * 2);       // [1280][1280]
    unsigned int* w12p = (unsigned int*)alloc(32768ull * 4);
    u16* xbf = (u16*)alloc(327680ull * 2);           // [256][1280]
    u16* h0 = (u16*)alloc(327680ull * 2);            // [256][1280]
    u16* h1 = (u16*)alloc(327680ull * 2);            // [256][1280]
    float* ghh0 = (float*)alloc(1310720ull * 4);     // [256][5120]
    float* ghh1 = (float*)alloc(1310720ull * 4);
    float* yb = (float*)alloc(327680ull * 4);        // [256][1280]
    float* ins_b = (float*)alloc(5120ull * 4);       // [256][20]
    unsigned* bar = (unsigned*)alloc(4096);          // barrier state (25 lines)

    // weight prep + state init
    cvt_wcat<<<25600, 256, 0, stream>>>(w_ih, w_hh, wcat);
    cvt_kernel<<<1600, 256, 0, stream>>>(w2_1, w21_bf, 1638400);
    cvt_w12p<<<128, 256, 0, stream>>>(w1_2, w12p);
    hipMemsetAsync(ghh0, 0, 1310720ull * 4, stream);   // h0(-1)=0 -> ghh0=0
    hipMemsetAsync(h1, 0, 327680ull * 2, stream);      // h1(-1)=0 (ghh1 computed in ph1 t=0)
    hipMemsetAsync(bar, 0, 4096, stream);

    k_persist<<<256, 256, 0, stream>>>(wcat, w21_bf, w12p, inputs, ps,
                                       w1_1, b1_1, b1_2, b_ih, b_hh, b2_1,
                                       w2_2, b2_2, out, xbf, h0, h1,
                                       ghh0, ghh1, yb, ins_b, bar);
}

// Round 3
// 8511.401 us; speedup vs baseline: 1.5105x; 1.4995x over previous
//
#include <hip/hip_runtime.h>

typedef unsigned short u16;
typedef __bf16 bf16x8 __attribute__((ext_vector_type(8)));
typedef float f32x4 __attribute__((ext_vector_type(4)));

#define AS1 __attribute__((address_space(1)))
#define AS3 __attribute__((address_space(3)))

// B=256, A=5, T=64, NIN=4, NHID=256, L=2, H=1280, 4H=5120, steps=63

__device__ __forceinline__ u16 f2bf(float f) {
    union { float f; unsigned int u; } v; v.f = f;
    unsigned int r = v.u + 0x7fffu + ((v.u >> 16) & 1u);
    return (u16)(r >> 16);
}

// aux=0      : normal cached path (weights — read-only, may stay in L2)
// aux=0x11   : SC0|SC1 — device-coherent, bypasses stale per-XCD L2 (activations)
template <int AUX>
__device__ __forceinline__ void ld_lds16(const u16* g, u16* l) {
    __builtin_amdgcn_global_load_lds((AS1 unsigned int*)(unsigned long long)(const void*)g,
                                     (AS3 unsigned int*)l, 16, 0, AUX);
}

// Coherent (device-scope) scalar/vector accessors for cross-block activations.
__device__ __forceinline__ float ld_f32_sc(const float* p) {
    return __hip_atomic_load((float*)p, __ATOMIC_RELAXED, __HIP_MEMORY_SCOPE_AGENT);
}
__device__ __forceinline__ void st_f32_sc(float* p, float v) {
    asm volatile("global_store_dword %0, %1, off sc0 sc1" :: "v"(p), "v"(v) : "memory");
}
__device__ __forceinline__ void st_f32x4_sc(float* p, f32x4 v) {
    asm volatile("global_store_dwordx4 %0, %1, off sc0 sc1" :: "v"(p), "v"(v) : "memory");
}
__device__ __forceinline__ void st_u16_sc(u16* p, unsigned v) {
    asm volatile("global_store_short %0, %1, off sc0 sc1" :: "v"(p), "v"(v) : "memory");
}

__device__ __forceinline__ float sigm(float x) { return 1.f / (1.f + __expf(-x)); }
__device__ __forceinline__ float tanh_f(float x) { return 1.f - 2.f / (__expf(2.f * x) + 1.f); }

// ---------------------------------------------------------------------------
// Weight-prep kernels (unchanged)
// ---------------------------------------------------------------------------
__global__ __launch_bounds__(256) void cvt_kernel(const float* __restrict__ src,
                                                  u16* __restrict__ dst, int n) {
    int i = (blockIdx.x * 256 + threadIdx.x) * 4;
    if (i >= n) return;
    float4 v = *(const float4*)(src + i);
    ushort4 o;
    o.x = f2bf(v.x); o.y = f2bf(v.y); o.z = f2bf(v.z); o.w = f2bf(v.w);
    *(ushort4*)(dst + i) = o;
}

__global__ __launch_bounds__(256) void cvt_wcat(const float* __restrict__ wih,
                                                const float* __restrict__ whh,
                                                u16* __restrict__ dst) {
    long long idx = ((long long)blockIdx.x * 256 + threadIdx.x) * 4;
    int k = (int)(idx % 2560);
    long long rr = idx / 2560;
    int l = (int)(rr / 5120), r = (int)(rr % 5120);
    int j = r >> 2, g = r & 3;
    long long srow = (long long)l * 5120 + g * 1280 + j;
    const float* s = (k < 1280) ? (wih + srow * 1280 + k) : (whh + srow * 1280 + (k - 1280));
    float4 v = *(const float4*)s;
    ushort4 o;
    o.x = f2bf(v.x); o.y = f2bf(v.y); o.z = f2bf(v.z); o.w = f2bf(v.w);
    *(ushort4*)(dst + idx) = o;
}

__global__ __launch_bounds__(256) void cvt_w12p(const float* __restrict__ w,
                                                unsigned int* __restrict__ dst) {
    int idx = blockIdx.x * 256 + threadIdx.x;  // 32768
    int kk = idx >> 8, j = idx & 255;
    float f0 = w[j * 256 + 2 * kk], f1 = w[j * 256 + 2 * kk + 1];
    dst[idx] = (unsigned)f2bf(f0) | ((unsigned)f2bf(f1) << 16);
}

// ---------------------------------------------------------------------------
// core64: 64x128 tile, K=1280 (20 iters), QUAD-buffered prefetch (depth 3).
// A-operand = activation (coherent sc loads); B-operand = weight (cached).
// As: 4 x 4096 u16 (32KB) at smem+0, Bs: 4 x 8192 u16 (64KB) at smem+32768.
// ---------------------------------------------------------------------------
__device__ __forceinline__ void core64(
    const u16* A, int lda, const u16* Bw, int ldb,
    int m0, int n0, u16* As, u16* Bs, f32x4 (&acc)[2][4]) {
    const int nIter = 20;
    int tid = threadIdx.x;
    int w = tid >> 6, l = tid & 63;
    int r8 = l >> 3, g8 = (l & 7) ^ r8;
    const u16* aP = A + (size_t)(m0 + w * 8 + r8) * lda + g8 * 8;
    const u16* bP = Bw + (size_t)(n0 + w * 8 + r8) * ldb + g8 * 8;
    u16* aD = As + w * 512;
    u16* bD = Bs + w * 512;

#define ISSUE64(it)                                            \
    {                                                          \
        int bsel = (it) & 3;                                   \
        const u16* ap = aP + (it) * 64;                        \
        const u16* bp = bP + (it) * 64;                        \
        u16* ad = aD + bsel * 4096;                            \
        u16* bd = bD + bsel * 8192;                            \
        ld_lds16<0x11>(ap, ad);                                \
        ld_lds16<0x11>(ap + (size_t)32 * lda, ad + 2048);      \
        ld_lds16<0>(bp, bd);                                   \
        ld_lds16<0>(bp + (size_t)32 * ldb, bd + 2048);         \
        ld_lds16<0>(bp + (size_t)64 * ldb, bd + 4096);         \
        ld_lds16<0>(bp + (size_t)96 * ldb, bd + 6144);         \
    }

    ISSUE64(0);
    ISSUE64(1);
    ISSUE64(2);
    int wm = w >> 1, wn = w & 1, q = l >> 4, m16 = l & 15;
    for (int it = 0; it < nIter; ++it) {
        if (it + 3 < nIter) ISSUE64(it + 3);
        int ahead = nIter - 1 - it; if (ahead > 3) ahead = 3;
        if (ahead == 3) asm volatile("s_waitcnt vmcnt(18)" ::: "memory");
        else if (ahead == 2) asm volatile("s_waitcnt vmcnt(12)" ::: "memory");
        else if (ahead == 1) asm volatile("s_waitcnt vmcnt(6)" ::: "memory");
        else asm volatile("s_waitcnt vmcnt(0)" ::: "memory");
        asm volatile("s_barrier" ::: "memory");
        const u16* as = As + (it & 3) * 4096;
        const u16* bs = Bs + (it & 3) * 8192;
#pragma unroll
        for (int ks = 0; ks < 2; ks++) {
            bf16x8 af[2], bfr[4];
            int gsw = (ks * 4 + q) ^ (m16 & 7);
#pragma unroll
            for (int i = 0; i < 2; i++) {
                int m = wm * 32 + i * 16 + m16;
                af[i] = *(const bf16x8*)&as[m * 64 + gsw * 8];
            }
#pragma unroll
            for (int j = 0; j < 4; j++) {
                int n = wn * 64 + j * 16 + m16;
                bfr[j] = *(const bf16x8*)&bs[n * 64 + gsw * 8];
            }
#pragma unroll
            for (int i = 0; i < 2; i++)
#pragma unroll
                for (int j = 0; j < 4; j++)
                    acc[i][j] = __builtin_amdgcn_mfma_f32_16x16x32_bf16(af[i], bfr[j], acc[i][j], 0, 0, 0);
        }
        asm volatile("s_barrier" ::: "memory");
    }
#undef ISSUE64
}

// ---------------------------------------------------------------------------
// core128: 128x128 tile, K=1280 (20 iters), triple-buffered (depth 2)
// As: 3 x 8192 u16 at smem+0, Bs: 3 x 8192 u16 at smem+49152.
// ---------------------------------------------------------------------------
__device__ __forceinline__ void core128(
    const u16* A, int lda, const u16* Bw, int ldb,
    int m0, int n0, u16* As, u16* Bs, f32x4 (&acc)[4][4]) {
    const int nIter = 20;
    int tid = threadIdx.x;
    int w = tid >> 6, l = tid & 63;
    int r8 = l >> 3, g8 = (l & 7) ^ r8;
    const u16* aP = A + (size_t)(m0 + w * 32 + r8) * lda + g8 * 8;
    const u16* bP = Bw + (size_t)(n0 + w * 32 + r8) * ldb + g8 * 8;
    u16* aD = As + w * 2048;
    u16* bD = Bs + w * 2048;

#define ISSUE128(it)                                           \
    {                                                          \
        int bsel = (it) % 3;                                   \
        const u16* ap = aP + (it) * 64;                        \
        const u16* bp = bP + (it) * 64;                        \
        u16* ad = aD + bsel * 8192;                            \
        u16* bd = bD + bsel * 8192;                            \
        ld_lds16<0x11>(ap, ad);                                \
        ld_lds16<0x11>(ap + (size_t)8 * lda, ad + 512);        \
        ld_lds16<0x11>(ap + (size_t)16 * lda, ad + 1024);      \
        ld_lds16<0x11>(ap + (size_t)24 * lda, ad + 1536);      \
        ld_lds16<0>(bp, bd);                                   \
        ld_lds16<0>(bp + (size_t)8 * ldb, bd + 512);           \
        ld_lds16<0>(bp + (size_t)16 * ldb, bd + 1024);         \
        ld_lds16<0>(bp + (size_t)24 * ldb, bd + 1536);         \
    }

    ISSUE128(0);
    ISSUE128(1);
    int wm = w >> 1, wn = w & 1, q = l >> 4, m16 = l & 15;
    for (int it = 0; it < nIter; ++it) {
        if (it + 2 < nIter) ISSUE128(it + 2);
        int ahead = nIter - 1 - it; if (ahead > 2) ahead = 2;
        if (ahead == 2) asm volatile("s_waitcnt vmcnt(16)" ::: "memory");
        else if (ahead == 1) asm volatile("s_waitcnt vmcnt(8)" ::: "memory");
        else asm volatile("s_waitcnt vmcnt(0)" ::: "memory");
        asm volatile("s_barrier" ::: "memory");
        const u16* as = As + (it % 3) * 8192;
        const u16* bs = Bs + (it % 3) * 8192;
#pragma unroll
        for (int ks = 0; ks < 2; ks++) {
            bf16x8 af[4], bfr[4];
            int gsw = (ks * 4 + q) ^ (m16 & 7);
#pragma unroll
            for (int i = 0; i < 4; i++) {
                int m = wm * 64 + i * 16 + m16;
                af[i] = *(const bf16x8*)&as[m * 64 + gsw * 8];
            }
#pragma unroll
            for (int j = 0; j < 4; j++) {
                int n = wn * 64 + j * 16 + m16;
                bfr[j] = *(const bf16x8*)&bs[n * 64 + gsw * 8];
            }
#pragma unroll
            for (int i = 0; i < 4; i++)
#pragma unroll
                for (int j = 0; j < 4; j++)
                    acc[i][j] = __builtin_amdgcn_mfma_f32_16x16x32_bf16(af[i], bfr[j], acc[i][j], 0, 0, 0);
        }
        asm volatile("s_barrier" ::: "memory");
    }
#undef ISSUE128
}

// ---------------------------------------------------------------------------
// Fence-free two-level grid barrier. All cross-block data moves through
// coherent (sc0|sc1) accesses, so NO buffer_wbl2 / buffer_inv is ever needed.
// Explicit vmcnt(0) drains the write-through stores before arrival.
// ---------------------------------------------------------------------------
__device__ __forceinline__ void grid_sync(unsigned* bar, unsigned ep) {
    asm volatile("s_waitcnt vmcnt(0)" ::: "memory");   // all waves: stores at coherence point
    __syncthreads();
    if (threadIdx.x == 0) {
        int bid = blockIdx.x;
        unsigned old = atomicAdd(&bar[(bid & 7) * 32], 1u);
        if (old == ep * 32u + 31u) {
            unsigned r = atomicAdd(&bar[8 * 32], 1u);
            if (r == ep * 8u + 7u) {
#pragma unroll
                for (int i = 0; i < 16; i++)
                    __hip_atomic_store(&bar[(9 + i) * 32], ep + 1u,
                                       __ATOMIC_RELAXED, __HIP_MEMORY_SCOPE_AGENT);
            }
        }
        while (__hip_atomic_load(&bar[(9 + (blockIdx.x & 15)) * 32], __ATOMIC_RELAXED,
                                 __HIP_MEMORY_SCOPE_AGENT) < ep + 1u)
            __builtin_amdgcn_s_sleep(8);
    }
    __syncthreads();
}

// ---------------------------------------------------------------------------
// Phase bodies
// ---------------------------------------------------------------------------
__device__ __forceinline__ void do_gates(
    int task, const u16* __restrict__ A, const u16* __restrict__ Bw,
    const float* __restrict__ ghh, const float* __restrict__ bih,
    const float* __restrict__ bhh, float (&creg)[8], u16* __restrict__ hout,
    char* smem) {
    u16* As = (u16*)smem;
    u16* Bs = (u16*)(smem + 32768);
    float (*cb)[132] = (float(*)[132])smem;   // overlay after core

    int nb = task % 40, mb = task / 40;
    int n0 = nb * 128, m0 = mb * 64;

    f32x4 acc[2][4];
#pragma unroll
    for (int i = 0; i < 2; i++)
#pragma unroll
        for (int j = 0; j < 4; j++) acc[i][j] = (f32x4){0.f, 0.f, 0.f, 0.f};

    core64(A, 1280, Bw, 2560, m0, n0, As, Bs, acc);

    int tid = threadIdx.x;
    int w = tid >> 6, l = tid & 63;
    int wm = w >> 1, wn = w & 1, q = l >> 4, m16 = l & 15;

    // batched coherent ghh loads (producer is on another XCD)
    float gv[2][4][4];
#pragma unroll
    for (int i = 0; i < 2; i++)
#pragma unroll
        for (int j = 0; j < 4; j++)
#pragma unroll
            for (int r = 0; r < 4; r++) {
                int rl = wm * 32 + i * 16 + q * 4 + r;
                int cl = wn * 64 + j * 16 + m16;
                gv[i][j][r] = ld_f32_sc(&ghh[(size_t)(m0 + rl) * 5120 + n0 + cl]);
            }
#pragma unroll
    for (int i = 0; i < 2; i++)
#pragma unroll
        for (int j = 0; j < 4; j++)
#pragma unroll
            for (int r = 0; r < 4; r++) {
                int rl = wm * 32 + i * 16 + q * 4 + r;
                int cl = wn * 64 + j * 16 + m16;
                cb[rl][cl] = acc[i][j][r] + gv[i][j][r];
            }
    __syncthreads();

    int jt = tid & 31, bt0 = tid >> 5;
    int jg = (n0 >> 2) + jt;
    float bI = bih[jg] + bhh[jg];
    float bF = bih[1280 + jg] + bhh[1280 + jg];
    float bG = bih[2560 + jg] + bhh[2560 + jg];
    float bO = bih[3840 + jg] + bhh[3840 + jg];
#pragma unroll
    for (int p = 0; p < 8; p++) {
        int bt = bt0 + p * 8;
        float4 g4 = *(const float4*)&cb[bt][jt * 4];   // i,f,g,o
        int b = m0 + bt;
        float cv = creg[p];                             // register-resident cell state
        float cn = sigm(g4.y + bF) * cv + sigm(g4.x + bI) * tanh_f(g4.z + bG);
        creg[p] = cn;
        st_u16_sc(&hout[(size_t)b * 1280 + jg], (unsigned)f2bf(sigm(g4.w + bO) * tanh_f(cn)));
    }
}

__device__ __forceinline__ void do_ghh(int task, const u16* __restrict__ Aop,
                                       const u16* __restrict__ Bop,
                                       float* __restrict__ G, char* smem) {
    u16* As = (u16*)smem;
    u16* Bs = (u16*)(smem + 49152);
    int mb = task / 40, nb = task % 40;
    int m0 = mb * 128, n0 = nb * 128;
    f32x4 acc[4][4];
#pragma unroll
    for (int i = 0; i < 4; i++)
#pragma unroll
        for (int j = 0; j < 4; j++) acc[i][j] = (f32x4){0.f, 0.f, 0.f, 0.f};
    core128(Aop, 1280, Bop, 2560, m0, n0, As, Bs, acc);
    int tid = threadIdx.x;
    int w = tid >> 6, l = tid & 63;
    int wm = w >> 1, wn = w & 1, q = l >> 4, m16 = l & 15;
#pragma unroll
    for (int i = 0; i < 4; i++) {
        int row = m0 + wm * 64 + i * 16 + q * 4;
#pragma unroll
        for (int j = 0; j < 4; j++) {
            int col = n0 + wn * 64 + j * 16 + m16;
            // rows are r=0..3 consecutive at fixed col -> 4 scalar sc stores;
            // use 4 dwords (column-strided), keep as scalars
#pragma unroll
            for (int r = 0; r < 4; r++)
                st_f32_sc(&G[(size_t)(row + r) * 5120 + col], acc[i][j][r]);
        }
    }
}

__device__ __forceinline__ void do_y(int task, const u16* __restrict__ h1,
                                     const u16* __restrict__ w21,
                                     const float* __restrict__ b21,
                                     float* __restrict__ yb, char* smem) {
    u16* As = (u16*)smem;
    u16* Bs = (u16*)(smem + 32768);
    int nb = task % 10, mb = task / 10;
    int n0 = nb * 128, m0 = mb * 64;
    f32x4 acc[2][4];
#pragma unroll
    for (int i = 0; i < 2; i++)
#pragma unroll
        for (int j = 0; j < 4; j++) acc[i][j] = (f32x4){0.f, 0.f, 0.f, 0.f};
    core64(h1, 1280, w21, 1280, m0, n0, As, Bs, acc);
    int tid = threadIdx.x;
    int w = tid >> 6, l = tid & 63;
    int wm = w >> 1, wn = w & 1, q = l >> 4, m16 = l & 15;
#pragma unroll
    for (int i = 0; i < 2; i++) {
        int row = m0 + wm * 32 + i * 16 + q * 4;
#pragma unroll
        for (int j = 0; j < 4; j++) {
            int col = n0 + wn * 64 + j * 16 + m16;
#pragma unroll
            for (int r = 0; r < 4; r++)
                st_f32_sc(&yb[(size_t)(row + r) * 1280 + col],
                          fmaxf(acc[i][j][r] + b21[col], 0.f));
        }
    }
}

__device__ __forceinline__ void do_head(bool first, int t, int b,
    const float* __restrict__ yb, const float* __restrict__ w22,
    const float* __restrict__ b22, const float* __restrict__ inputs,
    const int* __restrict__ ps, const float* __restrict__ w11,
    const float* __restrict__ b11, const unsigned int* __restrict__ w12p,
    const float* __restrict__ b12, float* __restrict__ out,
    float* __restrict__ ins_buf, u16* __restrict__ xnext, char* smem) {
    float* ins_s = (float*)smem;           // 20 floats
    float* redm = (float*)(smem + 128);    // [4][20]
    float* act1 = (float*)(smem + 512);    // 1280 floats
    int tid = threadIdx.x;
    int w = tid >> 6, l = tid & 63;
    int psv = ps[0];

    if (!first) {
        float acc[20];
#pragma unroll
        for (int j = 0; j < 20; j++) acc[j] = 0.f;
        const float* yrow = yb + (size_t)b * 1280;
        float yv[5];
#pragma unroll
        for (int s = 0; s < 5; s++)
            yv[s] = ld_f32_sc(&yrow[w * 320 + s * 64 + l]);   // coherent (ph3 writer on other XCD)
#pragma unroll
        for (int s = 0; s < 5; s++) {
            int k = w * 320 + s * 64 + l;
#pragma unroll
            for (int j = 0; j < 20; j++) acc[j] = fmaf(yv[s], w22[j * 1280 + k], acc[j]);
        }
#pragma unroll
        for (int j = 0; j < 20; j++)
#pragma unroll
            for (int off = 32; off; off >>= 1) acc[j] += __shfl_xor(acc[j], off);
        if (l < 20) redm[w * 20 + l] = acc[l];
        __syncthreads();
        if (tid < 20) {
            float o = redm[tid] + redm[20 + tid] + redm[40 + tid] + redm[60 + tid]
                      + b22[tid] + ins_buf[b * 20 + tid];     // ins_buf: same-block data
            int a = tid >> 2, n = tid & 3;
            out[(((size_t)b * 5 + a) * 63 + t) * 4 + n] = o;
            float nx = (((t + 1) % psv) == 0)
                           ? inputs[(((size_t)b * 5 + a) * 64 + (t + 1)) * 4 + n] : o;
            ins_s[tid] = nx;
            ins_buf[b * 20 + tid] = nx;
        }
    } else {
        if (tid < 20) {
            int a = tid >> 2, n = tid & 3;
            float nx = inputs[(((size_t)b * 5 + a) * 64) * 4 + n];
            ins_s[tid] = nx;
            ins_buf[b * 20 + tid] = nx;
        }
    }
    __syncthreads();

    int j = tid;
    float4 wv = *(const float4*)(w11 + j * 4);
    float bb = b11[j];
#pragma unroll
    for (int g = 0; g < 5; g++) {
        float v = fmaf(wv.x, ins_s[g * 4],
                  fmaf(wv.y, ins_s[g * 4 + 1],
                  fmaf(wv.z, ins_s[g * 4 + 2],
                  fmaf(wv.w, ins_s[g * 4 + 3], bb))));
        act1[g * 256 + j] = fmaxf(v, 0.f);
    }
    __syncthreads();

    float acc2[5];
    float bb2 = b12[j];
#pragma unroll
    for (int g = 0; g < 5; g++) acc2[g] = bb2;
    for (int kk = 0; kk < 128; kk++) {
        unsigned int pr = w12p[kk * 256 + j];
        union { unsigned int u; float f; } lo, hi;
        lo.u = pr << 16; hi.u = pr & 0xffff0000u;
#pragma unroll
        for (int g = 0; g < 5; g++)
            acc2[g] = fmaf(lo.f, act1[g * 256 + 2 * kk],
                      fmaf(hi.f, act1[g * 256 + 2 * kk + 1], acc2[g]));
    }
#pragma unroll
    for (int g = 0; g < 5; g++)
        st_u16_sc(&xnext[(size_t)b * 1280 + g * 256 + j], (unsigned)f2bf(fmaxf(acc2[g], 0.f)));
}

// ---------------------------------------------------------------------------
// Persistent kernel: 256 blocks (1/CU), all 63 steps, fence-free sync.
// ph1: gates0 (0..159) || ghh1' = h1(t-1)@whh1 (160..239)
// ph2: gates1 (0..159) || ghh0' = h0@whh0     (160..239)
// ph3: y = relu(h1@w21) (0..39)
// ph4: head/out/MLP -> x(t+1) (all 256)
// ---------------------------------------------------------------------------
__global__ __launch_bounds__(256, 1) void k_persist(
    const u16* __restrict__ wcat, const u16* __restrict__ w21,
    const unsigned int* __restrict__ w12p,
    const float* __restrict__ inputs, const int* __restrict__ ps,
    const float* __restrict__ w11, const float* __restrict__ b11,
    const float* __restrict__ b12,
    const float* __restrict__ bih, const float* __restrict__ bhh,
    const float* __restrict__ b21,
    const float* __restrict__ w22, const float* __restrict__ b22,
    float* __restrict__ out,
    u16* __restrict__ xbf, u16* __restrict__ h0, u16* __restrict__ h1,
    float* __restrict__ ghh0, float* __restrict__ ghh1,
    float* __restrict__ yb, float* __restrict__ ins_b,
    unsigned* __restrict__ bar) {
    __shared__ __align__(16) char smem[98304];
    int bid = blockIdx.x;
    unsigned ep = 0;
    float creg0[8], creg1[8];   // register-resident LSTM cell state (c=0 init)
#pragma unroll
    for (int p = 0; p < 8; p++) { creg0[p] = 0.f; creg1[p] = 0.f; }

    // phase 0: t=-1 head -> ins(0), x(0)
    do_head(true, -1, bid, yb, w22, b22, inputs, ps, w11, b11, w12p, b12,
            out, ins_b, xbf, smem);
    grid_sync(bar, ep); ep++;

    for (int t = 0; t < 63; ++t) {
        // ph1
        if (bid < 160)
            do_gates(bid, xbf, wcat, ghh0, bih, bhh, creg0, h0, smem);
        else if (bid < 240)
            do_ghh(bid - 160, h1, wcat + 13107200 + 1280, ghh1, smem);
        grid_sync(bar, ep); ep++;

        // ph2
        if (bid < 160)
            do_gates(bid, h0, wcat + 13107200, ghh1, bih + 5120, bhh + 5120,
                     creg1, h1, smem);
        else if (bid < 240)
            do_ghh(bid - 160, h0, wcat + 1280, ghh0, smem);
        grid_sync(bar, ep); ep++;

        // ph3
        if (bid < 40)
            do_y(bid, h1, w21, b21, yb, smem);
        grid_sync(bar, ep); ep++;

        // ph4
        do_head(false, t, bid, yb, w22, b22, inputs, ps, w11, b11, w12p, b12,
                out, ins_b, xbf, smem);
        grid_sync(bar, ep); ep++;
    }
}

// ---------------------------------------------------------------------------
extern "C" void kernel_launch(void* const* d_in, const int* in_sizes, int n_in,
                              void* d_out, int out_size, void* d_ws, size_t ws_size,
                              hipStream_t stream) {
    const float* inputs = (const float*)d_in[0];
    const float* w1_1 = (const float*)d_in[1];
    const float* b1_1 = (const float*)d_in[2];
    const float* w1_2 = (const float*)d_in[3];
    const float* b1_2 = (const float*)d_in[4];
    const float* w_ih = (const float*)d_in[5];
    const float* w_hh = (const float*)d_in[6];
    const float* b_ih = (const float*)d_in[7];
    const float* b_hh = (const float*)d_in[8];
    const float* w2_1 = (const float*)d_in[9];
    const float* b2_1 = (const float*)d_in[10];
    const float* w2_2 = (const float*)d_in[11];
    const float* b2_2 = (const float*)d_in[12];
    const int* ps = (const int*)d_in[13];
    float* out = (float*)d_out;

    char* ws = (char*)d_ws;
    size_t off = 0;
    auto alloc = [&](size_t bytes) -> void* {
        void* p = ws + off;
        off = (off + bytes + 255) & ~(size_t)255;
        return p;
    };
    u16* wcat = (u16*)alloc(26214400ull * 2);        // [2][5120][2560]
    u16* w21_bf = (u16*)alloc(1638400ull * 2);       // [1280][1280]
    unsigned int* w12p = (unsigned int*)alloc(32768ull * 4);
    u16* xbf = (u16*)alloc(327680ull * 2);           // [256][1280]
    u16* h0 = (u16*)alloc(327680ull * 2);            // [256][1280]
    u16* h1 = (u16*)alloc(327680ull * 2);            // [256][1280]
    float* ghh0 = (float*)alloc(1310720ull * 4);     // [256][5120]
    float* ghh1 = (float*)alloc(1310720ull * 4);
    float* yb = (float*)alloc(327680ull * 4);        // [256][1280]
    float* ins_b = (float*)alloc(5120ull * 4);       // [256][20]
    unsigned* bar = (unsigned*)alloc(4096);          // barrier state (25 lines)

    // weight prep + state init
    cvt_wcat<<<25600, 256, 0, stream>>>(w_ih, w_hh, wcat);
    cvt_kernel<<<1600, 256, 0, stream>>>(w2_1, w21_bf, 1638400);
    cvt_w12p<<<128, 256, 0, stream>>>(w1_2, w12p);
    hipMemsetAsync(ghh0, 0, 1310720ull * 4, stream);   // h0(-1)=0 -> ghh0=0
    hipMemsetAsync(h1, 0, 327680ull * 2, stream);      // h1(-1)=0 (ghh1 computed in ph1 t=0)
    hipMemsetAsync(bar, 0, 4096, stream);

    k_persist<<<256, 256, 0, stream>>>(wcat, w21_bf, w12p, inputs, ps,
                                       w1_1, b1_1, b1_2, b_ih, b_hh, b2_1,
                                       w2_2, b2_2, out, xbf, h0, h1,
                                       ghh0, ghh1, yb, ins_b, bar);
}

// Round 5
// 8168.449 us; speedup vs baseline: 1.5740x; 1.0420x over previous
//
#include <hip/hip_runtime.h>

typedef unsigned short u16;
typedef __bf16 bf16x8 __attribute__((ext_vector_type(8)));
typedef float f32x4 __attribute__((ext_vector_type(4)));

#define AS1 __attribute__((address_space(1)))
#define AS3 __attribute__((address_space(3)))

// B=256, A=5, T=64, NIN=4, NHID=256, L=2, H=1280, 4H=5120, steps=63

__device__ __forceinline__ u16 f2bf(float f) {
    union { float f; unsigned int u; } v; v.f = f;
    unsigned int r = v.u + 0x7fffu + ((v.u >> 16) & 1u);
    return (u16)(r >> 16);
}

__device__ __forceinline__ void ld_lds16(const u16* g, u16* l) {
    __builtin_amdgcn_global_load_lds((AS1 unsigned int*)(unsigned long long)(const void*)g,
                                     (AS3 unsigned int*)l, 16, 0, 0);
}

// Write-through (device-coherent) stores: L2 line never dirty, so the
// per-epoch acquire-inv can never discard data. ALL global stores in
// k_persist must use these.
__device__ __forceinline__ void st_f32_sc(float* p, float v) {
    asm volatile("global_store_dword %0, %1, off sc0 sc1" :: "v"(p), "v"(v) : "memory");
}
__device__ __forceinline__ void st_f32x4_sc(float* p, f32x4 v) {
    asm volatile("global_store_dwordx4 %0, %1, off sc0 sc1" :: "v"(p), "v"(v) : "memory");
}
__device__ __forceinline__ void st_u16_sc(u16* p, unsigned v) {
    asm volatile("global_store_short %0, %1, off sc0 sc1" :: "v"(p), "v"(v) : "memory");
}

__device__ __forceinline__ float sigm(float x) { return 1.f / (1.f + __expf(-x)); }
__device__ __forceinline__ float tanh_f(float x) { return 1.f - 2.f / (__expf(2.f * x) + 1.f); }

// ---------------------------------------------------------------------------
// Weight-prep kernels (unchanged)
// ---------------------------------------------------------------------------
__global__ __launch_bounds__(256) void cvt_kernel(const float* __restrict__ src,
                                                  u16* __restrict__ dst, int n) {
    int i = (blockIdx.x * 256 + threadIdx.x) * 4;
    if (i >= n) return;
    float4 v = *(const float4*)(src + i);
    ushort4 o;
    o.x = f2bf(v.x); o.y = f2bf(v.y); o.z = f2bf(v.z); o.w = f2bf(v.w);
    *(ushort4*)(dst + i) = o;
}

__global__ __launch_bounds__(256) void cvt_wcat(const float* __restrict__ wih,
                                                const float* __restrict__ whh,
                                                u16* __restrict__ dst) {
    long long idx = ((long long)blockIdx.x * 256 + threadIdx.x) * 4;
    int k = (int)(idx % 2560);
    long long rr = idx / 2560;
    int l = (int)(rr / 5120), r = (int)(rr % 5120);
    int j = r >> 2, g = r & 3;
    long long srow = (long long)l * 5120 + g * 1280 + j;
    const float* s = (k < 1280) ? (wih + srow * 1280 + k) : (whh + srow * 1280 + (k - 1280));
    float4 v = *(const float4*)s;
    ushort4 o;
    o.x = f2bf(v.x); o.y = f2bf(v.y); o.z = f2bf(v.z); o.w = f2bf(v.w);
    *(ushort4*)(dst + idx) = o;
}

__global__ __launch_bounds__(256) void cvt_w12p(const float* __restrict__ w,
                                                unsigned int* __restrict__ dst) {
    int idx = blockIdx.x * 256 + threadIdx.x;  // 32768
    int kk = idx >> 8, j = idx & 255;
    float f0 = w[j * 256 + 2 * kk], f1 = w[j * 256 + 2 * kk + 1];
    dst[idx] = (unsigned)f2bf(f0) | ((unsigned)f2bf(f1) << 16);
}

// ---------------------------------------------------------------------------
// core64: 64x128 tile, K=1280 (20 iters), QUAD-buffered prefetch (depth 3).
// Normal cached loads (L2 reuse); staleness handled by per-epoch acquire-inv.
// As: 4 x 4096 u16 (32KB) at smem+0, Bs: 4 x 8192 u16 (64KB) at smem+32768.
// ---------------------------------------------------------------------------
__device__ __forceinline__ void core64(
    const u16* A, int lda, const u16* Bw, int ldb,
    int m0, int n0, u16* As, u16* Bs, f32x4 (&acc)[2][4]) {
    const int nIter = 20;
    int tid = threadIdx.x;
    int w = tid >> 6, l = tid & 63;
    int r8 = l >> 3, g8 = (l & 7) ^ r8;
    const u16* aP = A + (size_t)(m0 + w * 8 + r8) * lda + g8 * 8;
    const u16* bP = Bw + (size_t)(n0 + w * 8 + r8) * ldb + g8 * 8;
    u16* aD = As + w * 512;
    u16* bD = Bs + w * 512;

#define ISSUE64(it)                                            \
    {                                                          \
        int bsel = (it) & 3;                                   \
        const u16* ap = aP + (it) * 64;                        \
        const u16* bp = bP + (it) * 64;                        \
        u16* ad = aD + bsel * 4096;                            \
        u16* bd = bD + bsel * 8192;                            \
        ld_lds16(ap, ad);                                      \
        ld_lds16(ap + (size_t)32 * lda, ad + 2048);            \
        ld_lds16(bp, bd);                                      \
        ld_lds16(bp + (size_t)32 * ldb, bd + 2048);            \
        ld_lds16(bp + (size_t)64 * ldb, bd + 4096);            \
        ld_lds16(bp + (size_t)96 * ldb, bd + 6144);            \
    }

    ISSUE64(0);
    ISSUE64(1);
    ISSUE64(2);
    int wm = w >> 1, wn = w & 1, q = l >> 4, m16 = l & 15;
    for (int it = 0; it < nIter; ++it) {
        if (it + 3 < nIter) ISSUE64(it + 3);
        int ahead = nIter - 1 - it; if (ahead > 3) ahead = 3;
        if (ahead == 3) asm volatile("s_waitcnt vmcnt(18)" ::: "memory");
        else if (ahead == 2) asm volatile("s_waitcnt vmcnt(12)" ::: "memory");
        else if (ahead == 1) asm volatile("s_waitcnt vmcnt(6)" ::: "memory");
        else asm volatile("s_waitcnt vmcnt(0)" ::: "memory");
        asm volatile("s_barrier" ::: "memory");
        const u16* as = As + (it & 3) * 4096;
        const u16* bs = Bs + (it & 3) * 8192;
#pragma unroll
        for (int ks = 0; ks < 2; ks++) {
            bf16x8 af[2], bfr[4];
            int gsw = (ks * 4 + q) ^ (m16 & 7);
#pragma unroll
            for (int i = 0; i < 2; i++) {
                int m = wm * 32 + i * 16 + m16;
                af[i] = *(const bf16x8*)&as[m * 64 + gsw * 8];
            }
#pragma unroll
            for (int j = 0; j < 4; j++) {
                int n = wn * 64 + j * 16 + m16;
                bfr[j] = *(const bf16x8*)&bs[n * 64 + gsw * 8];
            }
#pragma unroll
            for (int i = 0; i < 2; i++)
#pragma unroll
                for (int j = 0; j < 4; j++)
                    acc[i][j] = __builtin_amdgcn_mfma_f32_16x16x32_bf16(af[i], bfr[j], acc[i][j], 0, 0, 0);
        }
        asm volatile("s_barrier" ::: "memory");
    }
#undef ISSUE64
}

// ---------------------------------------------------------------------------
// core128: 128x128 tile, K=1280 (20 iters), triple-buffered (depth 2)
// As: 3 x 8192 u16 at smem+0, Bs: 3 x 8192 u16 at smem+49152.
// ---------------------------------------------------------------------------
__device__ __forceinline__ void core128(
    const u16* A, int lda, const u16* Bw, int ldb,
    int m0, int n0, u16* As, u16* Bs, f32x4 (&acc)[4][4]) {
    const int nIter = 20;
    int tid = threadIdx.x;
    int w = tid >> 6, l = tid & 63;
    int r8 = l >> 3, g8 = (l & 7) ^ r8;
    const u16* aP = A + (size_t)(m0 + w * 32 + r8) * lda + g8 * 8;
    const u16* bP = Bw + (size_t)(n0 + w * 32 + r8) * ldb + g8 * 8;
    u16* aD = As + w * 2048;
    u16* bD = Bs + w * 2048;

#define ISSUE128(it)                                           \
    {                                                          \
        int bsel = (it) % 3;                                   \
        const u16* ap = aP + (it) * 64;                        \
        const u16* bp = bP + (it) * 64;                        \
        u16* ad = aD + bsel * 8192;                            \
        u16* bd = bD + bsel * 8192;                            \
        ld_lds16(ap, ad);                                      \
        ld_lds16(ap + (size_t)8 * lda, ad + 512);              \
        ld_lds16(ap + (size_t)16 * lda, ad + 1024);            \
        ld_lds16(ap + (size_t)24 * lda, ad + 1536);            \
        ld_lds16(bp, bd);                                      \
        ld_lds16(bp + (size_t)8 * ldb, bd + 512);              \
        ld_lds16(bp + (size_t)16 * ldb, bd + 1024);            \
        ld_lds16(bp + (size_t)24 * ldb, bd + 1536);            \
    }

    ISSUE128(0);
    ISSUE128(1);
    int wm = w >> 1, wn = w & 1, q = l >> 4, m16 = l & 15;
    for (int it = 0; it < nIter; ++it) {
        if (it + 2 < nIter) ISSUE128(it + 2);
        int ahead = nIter - 1 - it; if (ahead > 2) ahead = 2;
        if (ahead == 2) asm volatile("s_waitcnt vmcnt(16)" ::: "memory");
        else if (ahead == 1) asm volatile("s_waitcnt vmcnt(8)" ::: "memory");
        else asm volatile("s_waitcnt vmcnt(0)" ::: "memory");
        asm volatile("s_barrier" ::: "memory");
        const u16* as = As + (it % 3) * 8192;
        const u16* bs = Bs + (it % 3) * 8192;
#pragma unroll
        for (int ks = 0; ks < 2; ks++) {
            bf16x8 af[4], bfr[4];
            int gsw = (ks * 4 + q) ^ (m16 & 7);
#pragma unroll
            for (int i = 0; i < 4; i++) {
                int m = wm * 64 + i * 16 + m16;
                af[i] = *(const bf16x8*)&as[m * 64 + gsw * 8];
            }
#pragma unroll
            for (int j = 0; j < 4; j++) {
                int n = wn * 64 + j * 16 + m16;
                bfr[j] = *(const bf16x8*)&bs[n * 64 + gsw * 8];
            }
#pragma unroll
            for (int i = 0; i < 4; i++)
#pragma unroll
                for (int j = 0; j < 4; j++)
                    acc[i][j] = __builtin_amdgcn_mfma_f32_16x16x32_bf16(af[i], bfr[j], acc[i][j], 0, 0, 0);
        }
        asm volatile("s_barrier" ::: "memory");
    }
#undef ISSUE128
}

// ---------------------------------------------------------------------------
// Grid barrier: release via write-through sc stores + vmcnt(0) drain (no wbl2);
// acquire via a single agent-scope ACQUIRE fence (buffer_inv, no writeback)
// executed by every wave after the barrier. Loads then use the normal cached
// path and can never see stale L1/L2 lines.
// ---------------------------------------------------------------------------
__device__ __forceinline__ void grid_sync(unsigned* bar, unsigned ep) {
    asm volatile("s_waitcnt vmcnt(0)" ::: "memory");   // sc stores at coherence point
    __syncthreads();
    if (threadIdx.x == 0) {
        int bid = blockIdx.x;
        unsigned old = atomicAdd(&bar[(bid & 7) * 32], 1u);
        if (old == ep * 32u + 31u) {
            unsigned r = atomicAdd(&bar[8 * 32], 1u);
            if (r == ep * 8u + 7u) {
#pragma unroll
                for (int i = 0; i < 16; i++)
                    __hip_atomic_store(&bar[(9 + i) * 32], ep + 1u,
                                       __ATOMIC_RELAXED, __HIP_MEMORY_SCOPE_AGENT);
            }
        }
        while (__hip_atomic_load(&bar[(9 + (blockIdx.x & 15)) * 32], __ATOMIC_RELAXED,
                                 __HIP_MEMORY_SCOPE_AGENT) < ep + 1u)
            __builtin_amdgcn_s_sleep(8);
    }
    __syncthreads();
    __builtin_amdgcn_fence(__ATOMIC_ACQUIRE, "agent");  // inv L1/L2 (clean — no loss)
}

// ---------------------------------------------------------------------------
// Phase bodies. ghh buffers are TRANSPOSED: G_T[col][sample], col 0..5119,
// sample 0..255 — the MFMA fragment's 4 consecutive rows become one float4.
// ---------------------------------------------------------------------------
__device__ __forceinline__ void do_gates(
    int task, const u16* __restrict__ A, const u16* __restrict__ Bw,
    const float* __restrict__ ghh, const float* __restrict__ bih,
    const float* __restrict__ bhh, float (&creg)[8], u16* __restrict__ hout,
    char* smem) {
    u16* As = (u16*)smem;
    u16* Bs = (u16*)(smem + 32768);
    float (*cb)[132] = (float(*)[132])smem;   // overlay after core

    int nb = task % 40, mb = task / 40;
    int n0 = nb * 128, m0 = mb * 64;

    f32x4 acc[2][4];
#pragma unroll
    for (int i = 0; i < 2; i++)
#pragma unroll
        for (int j = 0; j < 4; j++) acc[i][j] = (f32x4){0.f, 0.f, 0.f, 0.f};

    core64(A, 1280, Bw, 2560, m0, n0, As, Bs, acc);

    int tid = threadIdx.x;
    int w = tid >> 6, l = tid & 63;
    int wm = w >> 1, wn = w & 1, q = l >> 4, m16 = l & 15;
#pragma unroll
    for (int i = 0; i < 2; i++)
#pragma unroll
        for (int j = 0; j < 4; j++) {
            int rl = wm * 32 + i * 16 + q * 4;
            int cl = wn * 64 + j * 16 + m16;
            f32x4 gv = *(const f32x4*)&ghh[(size_t)(n0 + cl) * 256 + (m0 + rl)];
#pragma unroll
            for (int r = 0; r < 4; r++)
                cb[rl + r][cl] = acc[i][j][r] + gv[r];
        }
    __syncthreads();

    int jt = tid & 31, bt0 = tid >> 5;
    int jg = (n0 >> 2) + jt;
    float bI = bih[jg] + bhh[jg];
    float bF = bih[1280 + jg] + bhh[1280 + jg];
    float bG = bih[2560 + jg] + bhh[2560 + jg];
    float bO = bih[3840 + jg] + bhh[3840 + jg];
#pragma unroll
    for (int p = 0; p < 8; p++) {
        int bt = bt0 + p * 8;
        float4 g4 = *(const float4*)&cb[bt][jt * 4];   // i,f,g,o
        int b = m0 + bt;
        float cv = creg[p];                             // register-resident cell state
        float cn = sigm(g4.y + bF) * cv + sigm(g4.x + bI) * tanh_f(g4.z + bG);
        creg[p] = cn;
        st_u16_sc(&hout[(size_t)b * 1280 + jg], (unsigned)f2bf(sigm(g4.w + bO) * tanh_f(cn)));
    }
}

__device__ __forceinline__ void do_ghh(int task, const u16* __restrict__ Aop,
                                       const u16* __restrict__ Bop,
                                       float* __restrict__ G, char* smem) {
    u16* As = (u16*)smem;
    u16* Bs = (u16*)(smem + 49152);
    int mb = task / 40, nb = task % 40;
    int m0 = mb * 128, n0 = nb * 128;
    f32x4 acc[4][4];
#pragma unroll
    for (int i = 0; i < 4; i++)
#pragma unroll
        for (int j = 0; j < 4; j++) acc[i][j] = (f32x4){0.f, 0.f, 0.f, 0.f};
    core128(Aop, 1280, Bop, 2560, m0, n0, As, Bs, acc);
    int tid = threadIdx.x;
    int w = tid >> 6, l = tid & 63;
    int wm = w >> 1, wn = w & 1, q = l >> 4, m16 = l & 15;
#pragma unroll
    for (int i = 0; i < 4; i++) {
        int row = m0 + wm * 64 + i * 16 + q * 4;
#pragma unroll
        for (int j = 0; j < 4; j++) {
            int col = n0 + wn * 64 + j * 16 + m16;
            st_f32x4_sc(&G[(size_t)col * 256 + row], acc[i][j]);  // 4 rows -> one dwordx4
        }
    }
}

__device__ __forceinline__ void do_y(int task, const u16* __restrict__ h1,
                                     const u16* __restrict__ w21,
                                     const float* __restrict__ b21,
                                     float* __restrict__ yb, char* smem) {
    u16* As = (u16*)smem;
    u16* Bs = (u16*)(smem + 32768);
    int nb = task % 10, mb = task / 10;
    int n0 = nb * 128, m0 = mb * 64;
    f32x4 acc[2][4];
#pragma unroll
    for (int i = 0; i < 2; i++)
#pragma unroll
        for (int j = 0; j < 4; j++) acc[i][j] = (f32x4){0.f, 0.f, 0.f, 0.f};
    core64(h1, 1280, w21, 1280, m0, n0, As, Bs, acc);
    int tid = threadIdx.x;
    int w = tid >> 6, l = tid & 63;
    int wm = w >> 1, wn = w & 1, q = l >> 4, m16 = l & 15;
#pragma unroll
    for (int i = 0; i < 2; i++) {
        int row = m0 + wm * 32 + i * 16 + q * 4;
#pragma unroll
        for (int j = 0; j < 4; j++) {
            int col = n0 + wn * 64 + j * 16 + m16;
#pragma unroll
            for (int r = 0; r < 4; r++)
                st_f32_sc(&yb[(size_t)(row + r) * 1280 + col],
                          fmaxf(acc[i][j][r] + b21[col], 0.f));
        }
    }
}

__device__ __forceinline__ void do_head(bool first, int t, int b,
    const float* __restrict__ yb, const float* __restrict__ w22,
    const float* __restrict__ b22, const float* __restrict__ inputs,
    const int* __restrict__ ps, const float* __restrict__ w11,
    const float* __restrict__ b11, const unsigned int* __restrict__ w12p,
    const float* __restrict__ b12, float* __restrict__ out,
    float* __restrict__ ins_buf, u16* __restrict__ xnext, char* smem) {
    float* ins_s = (float*)smem;           // 20 floats
    float* redm = (float*)(smem + 128);    // [4][20]
    float* act1 = (float*)(smem + 512);    // 1280 floats
    int tid = threadIdx.x;
    int w = tid >> 6, l = tid & 63;
    int psv = ps[0];

    if (!first) {
        float acc[20];
#pragma unroll
        for (int j = 0; j < 20; j++) acc[j] = 0.f;
        const float* yrow = yb + (size_t)b * 1280;
#pragma unroll
        for (int s = 0; s < 5; s++) {
            int k = w * 320 + s * 64 + l;
            float yv = yrow[k];
#pragma unroll
            for (int j = 0; j < 20; j++) acc[j] = fmaf(yv, w22[j * 1280 + k], acc[j]);
        }
#pragma unroll
        for (int j = 0; j < 20; j++)
#pragma unroll
            for (int off = 32; off; off >>= 1) acc[j] += __shfl_xor(acc[j], off);
        if (l < 20) redm[w * 20 + l] = acc[l];
        __syncthreads();
        if (tid < 20) {
            float o = redm[tid] + redm[20 + tid] + redm[40 + tid] + redm[60 + tid]
                      + b22[tid] + ins_buf[b * 20 + tid];
            int a = tid >> 2, n = tid & 3;
            st_f32_sc(&out[(((size_t)b * 5 + a) * 63 + t) * 4 + n], o);
            float nx = (((t + 1) % psv) == 0)
                           ? inputs[(((size_t)b * 5 + a) * 64 + (t + 1)) * 4 + n] : o;
            ins_s[tid] = nx;
            st_f32_sc(&ins_buf[b * 20 + tid], nx);
        }
    } else {
        if (tid < 20) {
            int a = tid >> 2, n = tid & 3;
            float nx = inputs[(((size_t)b * 5 + a) * 64) * 4 + n];
            ins_s[tid] = nx;
            st_f32_sc(&ins_buf[b * 20 + tid], nx);
        }
    }
    __syncthreads();

    int j = tid;
    float4 wv = *(const float4*)(w11 + j * 4);
    float bb = b11[j];
#pragma unroll
    for (int g = 0; g < 5; g++) {
        float v = fmaf(wv.x, ins_s[g * 4],
                  fmaf(wv.y, ins_s[g * 4 + 1],
                  fmaf(wv.z, ins_s[g * 4 + 2],
                  fmaf(wv.w, ins_s[g * 4 + 3], bb))));
        act1[g * 256 + j] = fmaxf(v, 0.f);
    }
    __syncthreads();

    float acc2[5];
    float bb2 = b12[j];
#pragma unroll
    for (int g = 0; g < 5; g++) acc2[g] = bb2;
    for (int kk = 0; kk < 128; kk++) {
        unsigned int pr = w12p[kk * 256 + j];
        union { unsigned int u; float f; } lo, hi;
        lo.u = pr << 16; hi.u = pr & 0xffff0000u;
#pragma unroll
        for (int g = 0; g < 5; g++)
            acc2[g] = fmaf(lo.f, act1[g * 256 + 2 * kk],
                      fmaf(hi.f, act1[g * 256 + 2 * kk + 1], acc2[g]));
    }
#pragma unroll
    for (int g = 0; g < 5; g++)
        st_u16_sc(&xnext[(size_t)b * 1280 + g * 256 + j], (unsigned)f2bf(fmaxf(acc2[g], 0.f)));
}

// ---------------------------------------------------------------------------
// Persistent kernel: 256 blocks (1/CU), all 63 steps.
// ph1: gates0 (0..159) || ghh1' = h1(t-1)@whh1 (160..239)
// ph2: gates1 (0..159) || ghh0' = h0@whh0     (160..239)
// ph3: y = relu(h1@w21) (0..39)
// ph4: head/out/MLP -> x(t+1) (all 256)
// ---------------------------------------------------------------------------
__global__ __launch_bounds__(256, 1) void k_persist(
    const u16* __restrict__ wcat, const u16* __restrict__ w21,
    const unsigned int* __restrict__ w12p,
    const float* __restrict__ inputs, const int* __restrict__ ps,
    const float* __restrict__ w11, const float* __restrict__ b11,
    const float* __restrict__ b12,
    const float* __restrict__ bih, const float* __restrict__ bhh,
    const float* __restrict__ b21,
    const float* __restrict__ w22, const float* __restrict__ b22,
    float* __restrict__ out,
    u16* __restrict__ xbf, u16* __restrict__ h0, u16* __restrict__ h1,
    float* __restrict__ ghh0, float* __restrict__ ghh1,
    float* __restrict__ yb, float* __restrict__ ins_b,
    unsigned* __restrict__ bar) {
    __shared__ __align__(16) char smem[98304];
    int bid = blockIdx.x;
    unsigned ep = 0;
    float creg0[8], creg1[8];   // register-resident LSTM cell state (c=0 init)
#pragma unroll
    for (int p = 0; p < 8; p++) { creg0[p] = 0.f; creg1[p] = 0.f; }

    // phase 0: t=-1 head -> ins(0), x(0)
    do_head(true, -1, bid, yb, w22, b22, inputs, ps, w11, b11, w12p, b12,
            out, ins_b, xbf, smem);
    grid_sync(bar, ep); ep++;

    for (int t = 0; t < 63; ++t) {
        // ph1
        if (bid < 160)
            do_gates(bid, xbf, wcat, ghh0, bih, bhh, creg0, h0, smem);
        else if (bid < 240)
            do_ghh(bid - 160, h1, wcat + 13107200 + 1280, ghh1, smem);
        grid_sync(bar, ep); ep++;

        // ph2
        if (bid < 160)
            do_gates(bid, h0, wcat + 13107200, ghh1, bih + 5120, bhh + 5120,
                     creg1, h1, smem);
        else if (bid < 240)
            do_ghh(bid - 160, h0, wcat + 1280, ghh0, smem);
        grid_sync(bar, ep); ep++;

        // ph3
        if (bid < 40)
            do_y(bid, h1, w21, b21, yb, smem);
        grid_sync(bar, ep); ep++;

        // ph4
        do_head(false, t, bid, yb, w22, b22, inputs, ps, w11, b11, w12p, b12,
                out, ins_b, xbf, smem);
        grid_sync(bar, ep); ep++;
    }
}

// ---------------------------------------------------------------------------
extern "C" void kernel_launch(void* const* d_in, const int* in_sizes, int n_in,
                              void* d_out, int out_size, void* d_ws, size_t ws_size,
                              hipStream_t stream) {
    const float* inputs = (const float*)d_in[0];
    const float* w1_1 = (const float*)d_in[1];
    const float* b1_1 = (const float*)d_in[2];
    const float* w1_2 = (const float*)d_in[3];
    const float* b1_2 = (const float*)d_in[4];
    const float* w_ih = (const float*)d_in[5];
    const float* w_hh = (const float*)d_in[6];
    const float* b_ih = (const float*)d_in[7];
    const float* b_hh = (const float*)d_in[8];
    const float* w2_1 = (const float*)d_in[9];
    const float* b2_1 = (const float*)d_in[10];
    const float* w2_2 = (const float*)d_in[11];
    const float* b2_2 = (const float*)d_in[12];
    const int* ps = (const int*)d_in[13];
    float* out = (float*)d_out;

    char* ws = (char*)d_ws;
    size_t off = 0;
    auto alloc = [&](size_t bytes) -> void* {
        void* p = ws + off;
        off = (off + bytes + 255) & ~(size_t)255;
        return p;
    };
    u16* wcat = (u16*)alloc(26214400ull * 2);        // [2][5120][2560]
    u16* w21_bf = (u16*)alloc(1638400ull * 2);       // [1280][1280]
    unsigned int* w12p = (unsigned int*)alloc(32768ull * 4);
    u16* xbf = (u16*)alloc(327680ull * 2);           // [256][1280]
    u16* h0 = (u16*)alloc(327680ull * 2);            // [256][1280]
    u16* h1 = (u16*)alloc(327680ull * 2);            // [256][1280]
    float* ghh0 = (float*)alloc(1310720ull * 4);     // [5120][256] (transposed)
    float* ghh1 = (float*)alloc(1310720ull * 4);     // [5120][256] (transposed)
    float* yb = (float*)alloc(327680ull * 4);        // [256][1280]
    float* ins_b = (float*)alloc(5120ull * 4);       // [256][20]
    unsigned* bar = (unsigned*)alloc(4096);          // barrier state (25 lines)

    // weight prep + state init
    cvt_wcat<<<25600, 256, 0, stream>>>(w_ih, w_hh, wcat);
    cvt_kernel<<<1600, 256, 0, stream>>>(w2_1, w21_bf, 1638400);
    cvt_w12p<<<128, 256, 0, stream>>>(w1_2, w12p);
    hipMemsetAsync(ghh0, 0, 1310720ull * 4, stream);   // h0(-1)=0 -> ghh0=0
    hipMemsetAsync(h1, 0, 327680ull * 2, stream);      // h1(-1)=0 (ghh1 computed in ph1 t=0)
    hipMemsetAsync(bar, 0, 4096, stream);

    k_persist<<<256, 256, 0, stream>>>(wcat, w21_bf, w12p, inputs, ps,
                                       w1_1, b1_1, b1_2, b_ih, b_hh, b2_1,
                                       w2_2, b2_2, out, xbf, h0, h1,
                                       ghh0, ghh1, yb, ins_b, bar);
}

// Round 6
// 4501.286 us; speedup vs baseline: 2.8563x; 1.8147x over previous
//
#include <hip/hip_runtime.h>

typedef unsigned short u16;
typedef __bf16 bf16x8 __attribute__((ext_vector_type(8)));
typedef float f32x4 __attribute__((ext_vector_type(4)));

#define AS1 __attribute__((address_space(1)))
#define AS3 __attribute__((address_space(3)))

// B=256, A=5, T=64, NIN=4, NHID=256, L=2, H=1280, 4H=5120, steps=63

__device__ __forceinline__ u16 f2bf(float f) {
    union { float f; unsigned int u; } v; v.f = f;
    unsigned int r = v.u + 0x7fffu + ((v.u >> 16) & 1u);
    return (u16)(r >> 16);
}

__device__ __forceinline__ void ld_lds16(const u16* g, u16* l) {
    __builtin_amdgcn_global_load_lds((AS1 unsigned int*)(unsigned long long)(const void*)g,
                                     (AS3 unsigned int*)l, 16, 0, 0);
}

__device__ __forceinline__ float sigm(float x) { return 1.f / (1.f + __expf(-x)); }
__device__ __forceinline__ float tanh_f(float x) { return 1.f - 2.f / (__expf(2.f * x) + 1.f); }

// ---------------------------------------------------------------------------
// Weight-prep kernels
// ---------------------------------------------------------------------------
__global__ __launch_bounds__(256) void cvt_kernel(const float* __restrict__ src,
                                                  u16* __restrict__ dst, int n) {
    int i = (blockIdx.x * 256 + threadIdx.x) * 4;
    if (i >= n) return;
    float4 v = *(const float4*)(src + i);
    ushort4 o;
    o.x = f2bf(v.x); o.y = f2bf(v.y); o.z = f2bf(v.z); o.w = f2bf(v.w);
    *(ushort4*)(dst + i) = o;
}

// wcat[l][j*4+g][k]: k<1280 -> w_ih[l][g*1280+j][k], else w_hh[..][k-1280]
__global__ __launch_bounds__(256) void cvt_wcat(const float* __restrict__ wih,
                                                const float* __restrict__ whh,
                                                u16* __restrict__ dst) {
    long long idx = ((long long)blockIdx.x * 256 + threadIdx.x) * 4;
    int k = (int)(idx % 2560);
    long long rr = idx / 2560;
    int l = (int)(rr / 5120), r = (int)(rr % 5120);
    int j = r >> 2, g = r & 3;
    long long srow = (long long)l * 5120 + g * 1280 + j;
    const float* s = (k < 1280) ? (wih + srow * 1280 + k) : (whh + srow * 1280 + (k - 1280));
    float4 v = *(const float4*)s;
    ushort4 o;
    o.x = f2bf(v.x); o.y = f2bf(v.y); o.z = f2bf(v.z); o.w = f2bf(v.w);
    *(ushort4*)(dst + idx) = o;
}

__global__ __launch_bounds__(256) void cvt_w12p(const float* __restrict__ w,
                                                unsigned int* __restrict__ dst) {
    int idx = blockIdx.x * 256 + threadIdx.x;  // 32768
    int kk = idx >> 8, j = idx & 255;
    float f0 = w[j * 256 + 2 * kk], f1 = w[j * 256 + 2 * kk + 1];
    dst[idx] = (unsigned)f2bf(f0) | ((unsigned)f2bf(f1) << 16);
}

// ---------------------------------------------------------------------------
// core64d<NITER>: 64x128 tile, K = NITER*64, quad-buffered prefetch (depth 3).
// A operand comes from TWO sources: A1 for k<1280 (iters 0..19), A2 for
// k>=1280 (iters 20..39) — the fused [x ; h_prev] concat. For NITER=20 the
// A2 branch is dead. As: 4 x 4096 u16 (32KB) @0, Bs: 4 x 8192 (64KB) @32768.
// ---------------------------------------------------------------------------
template <int NITER>
__device__ __forceinline__ void core64d(
    const u16* A1, const u16* A2, int lda,
    const u16* Bw, int ldb,
    int m0, int n0, u16* As, u16* Bs, f32x4 (&acc)[2][4]) {
    int tid = threadIdx.x;
    int w = tid >> 6, l = tid & 63;
    int r8 = l >> 3, g8 = (l & 7) ^ r8;
    const u16* aP1 = A1 + (size_t)(m0 + w * 8 + r8) * lda + g8 * 8;
    const u16* aP2 = A2 + (size_t)(m0 + w * 8 + r8) * lda + g8 * 8;
    const u16* bP = Bw + (size_t)(n0 + w * 8 + r8) * ldb + g8 * 8;
    u16* aD = As + w * 512;
    u16* bD = Bs + w * 512;

#define ISSUE64(it)                                                        \
    {                                                                      \
        int bsel = (it) & 3;                                               \
        const u16* ap = ((it) < 20) ? (aP1 + (it) * 64)                    \
                                    : (aP2 + ((it) - 20) * 64);            \
        const u16* bp = bP + (it) * 64;                                    \
        u16* ad = aD + bsel * 4096;                                        \
        u16* bd = bD + bsel * 8192;                                        \
        ld_lds16(ap, ad);                                                  \
        ld_lds16(ap + (size_t)32 * lda, ad + 2048);                        \
        ld_lds16(bp, bd);                                                  \
        ld_lds16(bp + (size_t)32 * ldb, bd + 2048);                        \
        ld_lds16(bp + (size_t)64 * ldb, bd + 4096);                        \
        ld_lds16(bp + (size_t)96 * ldb, bd + 6144);                        \
    }

    ISSUE64(0);
    ISSUE64(1);
    ISSUE64(2);
    int wm = w >> 1, wn = w & 1, q = l >> 4, m16 = l & 15;
    for (int it = 0; it < NITER; ++it) {
        if (it + 3 < NITER) ISSUE64(it + 3);
        int ahead = NITER - 1 - it; if (ahead > 3) ahead = 3;
        if (ahead == 3) asm volatile("s_waitcnt vmcnt(18)" ::: "memory");
        else if (ahead == 2) asm volatile("s_waitcnt vmcnt(12)" ::: "memory");
        else if (ahead == 1) asm volatile("s_waitcnt vmcnt(6)" ::: "memory");
        else asm volatile("s_waitcnt vmcnt(0)" ::: "memory");
        asm volatile("s_barrier" ::: "memory");
        const u16* as = As + (it & 3) * 4096;
        const u16* bs = Bs + (it & 3) * 8192;
#pragma unroll
        for (int ks = 0; ks < 2; ks++) {
            bf16x8 af[2], bfr[4];
            int gsw = (ks * 4 + q) ^ (m16 & 7);
#pragma unroll
            for (int i = 0; i < 2; i++) {
                int m = wm * 32 + i * 16 + m16;
                af[i] = *(const bf16x8*)&as[m * 64 + gsw * 8];
            }
#pragma unroll
            for (int j = 0; j < 4; j++) {
                int n = wn * 64 + j * 16 + m16;
                bfr[j] = *(const bf16x8*)&bs[n * 64 + gsw * 8];
            }
#pragma unroll
            for (int i = 0; i < 2; i++)
#pragma unroll
                for (int j = 0; j < 4; j++)
                    acc[i][j] = __builtin_amdgcn_mfma_f32_16x16x32_bf16(af[i], bfr[j], acc[i][j], 0, 0, 0);
        }
        asm volatile("s_barrier" ::: "memory");
    }
#undef ISSUE64
}

// ---------------------------------------------------------------------------
// k_gates: FUSED gates_l = [x|h_prev](256x2560) @ wcat_l^T (K=2560, 40 iters)
// + fused LSTM cell. 160 blocks (4m x 40n). c: per-thread global fp32 RMW.
// ---------------------------------------------------------------------------
__global__ __launch_bounds__(256) void k_gates(
    const u16* __restrict__ A1, const u16* __restrict__ A2,
    const u16* __restrict__ Bw,
    const float* __restrict__ bih, const float* __restrict__ bhh,
    float* __restrict__ cst, u16* __restrict__ hout) {
    __shared__ __align__(16) char smem[98304];
    u16* As = (u16*)smem;
    u16* Bs = (u16*)(smem + 32768);
    float (*cb)[132] = (float(*)[132])smem;   // overlay after core

    int blk = blockIdx.x;
    int nb = blk % 40, mb = blk / 40;
    int n0 = nb * 128, m0 = mb * 64;

    f32x4 acc[2][4];
#pragma unroll
    for (int i = 0; i < 2; i++)
#pragma unroll
        for (int j = 0; j < 4; j++) acc[i][j] = (f32x4){0.f, 0.f, 0.f, 0.f};

    core64d<40>(A1, A2, 1280, Bw, 2560, m0, n0, As, Bs, acc);

    int tid = threadIdx.x;
    int w = tid >> 6, l = tid & 63;
    int wm = w >> 1, wn = w & 1, q = l >> 4, m16 = l & 15;
#pragma unroll
    for (int i = 0; i < 2; i++)
#pragma unroll
        for (int j = 0; j < 4; j++)
#pragma unroll
            for (int r = 0; r < 4; r++) {
                int rl = wm * 32 + i * 16 + q * 4 + r;
                int cl = wn * 64 + j * 16 + m16;
                cb[rl][cl] = acc[i][j][r];
            }
    __syncthreads();

    int jt = tid & 31, bt0 = tid >> 5;
    int jg = (n0 >> 2) + jt;
    float bI = bih[jg] + bhh[jg];
    float bF = bih[1280 + jg] + bhh[1280 + jg];
    float bG = bih[2560 + jg] + bhh[2560 + jg];
    float bO = bih[3840 + jg] + bhh[3840 + jg];
#pragma unroll
    for (int p = 0; p < 8; p++) {
        int bt = bt0 + p * 8;
        float4 g4 = *(const float4*)&cb[bt][jt * 4];   // i,f,g,o
        int b = m0 + bt;
        float cv = cst[b * 1280 + jg];
        float cn = sigm(g4.y + bF) * cv + sigm(g4.x + bI) * tanh_f(g4.z + bG);
        cst[b * 1280 + jg] = cn;
        hout[(size_t)b * 1280 + jg] = f2bf(sigm(g4.w + bO) * tanh_f(cn));
    }
}

// ---------------------------------------------------------------------------
// k_y: y = relu(h1 @ w21^T + b21), 40 blocks (4m x 10n), K=1280 (20 iters).
// ---------------------------------------------------------------------------
__global__ __launch_bounds__(256) void k_y(
    const u16* __restrict__ h1, const u16* __restrict__ w21,
    const float* __restrict__ b21, float* __restrict__ yb) {
    __shared__ __align__(16) char smem[98304];
    u16* As = (u16*)smem;
    u16* Bs = (u16*)(smem + 32768);
    int blk = blockIdx.x;
    int nb = blk % 10, mb = blk / 10;
    int n0 = nb * 128, m0 = mb * 64;
    f32x4 acc[2][4];
#pragma unroll
    for (int i = 0; i < 2; i++)
#pragma unroll
        for (int j = 0; j < 4; j++) acc[i][j] = (f32x4){0.f, 0.f, 0.f, 0.f};
    core64d<20>(h1, h1, 1280, w21, 1280, m0, n0, As, Bs, acc);
    int tid = threadIdx.x;
    int w = tid >> 6, l = tid & 63;
    int wm = w >> 1, wn = w & 1, q = l >> 4, m16 = l & 15;
#pragma unroll
    for (int i = 0; i < 2; i++) {
        int row = m0 + wm * 32 + i * 16 + q * 4;
#pragma unroll
        for (int j = 0; j < 4; j++) {
            int col = n0 + wn * 64 + j * 16 + m16;
#pragma unroll
            for (int r = 0; r < 4; r++)
                yb[(size_t)(row + r) * 1280 + col] = fmaxf(acc[i][j][r] + b21[col], 0.f);
        }
    }
}

// ---------------------------------------------------------------------------
// k_out: out head (y@w22^T + b22 + ins) -> d_out, teacher-select ins(t+1),
// MLP layer-1, MLP layer-2 -> x(t+1) bf16 [256][1280]. 256 blocks (1/sample).
// ---------------------------------------------------------------------------
template <int FIRST>
__global__ __launch_bounds__(256) void k_out(
    const float* __restrict__ yb, const float* __restrict__ w22,
    const float* __restrict__ b22, const float* __restrict__ inputs,
    const int* __restrict__ ps, const float* __restrict__ w11,
    const float* __restrict__ b11, const unsigned int* __restrict__ w12p,
    const float* __restrict__ b12, float* __restrict__ out,
    float* __restrict__ ins_buf, u16* __restrict__ xnext, int t) {
    __shared__ float ins_s[20];
    __shared__ float act1[5 * 256];
    __shared__ float red[4][20];
    int b = blockIdx.x, tid = threadIdx.x;
    int w = tid >> 6, l = tid & 63;
    int psv = ps[0];

    if (!FIRST) {
        float acc[20];
#pragma unroll
        for (int j = 0; j < 20; j++) acc[j] = 0.f;
        const float* yrow = yb + (size_t)b * 1280;
#pragma unroll
        for (int s = 0; s < 5; s++) {
            int k = w * 320 + s * 64 + l;
            float yv = yrow[k];
#pragma unroll
            for (int j = 0; j < 20; j++) acc[j] = fmaf(yv, w22[j * 1280 + k], acc[j]);
        }
#pragma unroll
        for (int j = 0; j < 20; j++)
#pragma unroll
            for (int off = 32; off; off >>= 1) acc[j] += __shfl_xor(acc[j], off);
        if (l < 20) red[w][l] = acc[l];
        __syncthreads();
        if (tid < 20) {
            float o = red[0][tid] + red[1][tid] + red[2][tid] + red[3][tid]
                      + b22[tid] + ins_buf[b * 20 + tid];
            int a = tid >> 2, n = tid & 3;
            out[(((size_t)b * 5 + a) * 63 + t) * 4 + n] = o;
            float nx = (((t + 1) % psv) == 0)
                           ? inputs[(((size_t)b * 5 + a) * 64 + (t + 1)) * 4 + n] : o;
            ins_s[tid] = nx;
            ins_buf[b * 20 + tid] = nx;
        }
    } else {
        if (tid < 20) {
            int a = tid >> 2, n = tid & 3;
            float nx = inputs[(((size_t)b * 5 + a) * 64) * 4 + n];
            ins_s[tid] = nx;
            ins_buf[b * 20 + tid] = nx;
        }
    }
    __syncthreads();

    int j = tid;
    float4 wv = *(const float4*)(w11 + j * 4);
    float bb = b11[j];
#pragma unroll
    for (int g = 0; g < 5; g++) {
        float v = fmaf(wv.x, ins_s[g * 4],
                  fmaf(wv.y, ins_s[g * 4 + 1],
                  fmaf(wv.z, ins_s[g * 4 + 2],
                  fmaf(wv.w, ins_s[g * 4 + 3], bb))));
        act1[g * 256 + j] = fmaxf(v, 0.f);
    }
    __syncthreads();

    float acc2[5];
    float bb2 = b12[j];
#pragma unroll
    for (int g = 0; g < 5; g++) acc2[g] = bb2;
    for (int kk = 0; kk < 128; kk++) {
        unsigned int pr = w12p[kk * 256 + j];
        union { unsigned int u; float f; } lo, hi;
        lo.u = pr << 16; hi.u = pr & 0xffff0000u;
#pragma unroll
        for (int g = 0; g < 5; g++)
            acc2[g] = fmaf(lo.f, act1[g * 256 + 2 * kk],
                      fmaf(hi.f, act1[g * 256 + 2 * kk + 1], acc2[g]));
    }
#pragma unroll
    for (int g = 0; g < 5; g++)
        xnext[(size_t)b * 1280 + g * 256 + j] = f2bf(fmaxf(acc2[g], 0.f));
}

// ---------------------------------------------------------------------------
extern "C" void kernel_launch(void* const* d_in, const int* in_sizes, int n_in,
                              void* d_out, int out_size, void* d_ws, size_t ws_size,
                              hipStream_t stream) {
    const float* inputs = (const float*)d_in[0];
    const float* w1_1 = (const float*)d_in[1];
    const float* b1_1 = (const float*)d_in[2];
    const float* w1_2 = (const float*)d_in[3];
    const float* b1_2 = (const float*)d_in[4];
    const float* w_ih = (const float*)d_in[5];
    const float* w_hh = (const float*)d_in[6];
    const float* b_ih = (const float*)d_in[7];
    const float* b_hh = (const float*)d_in[8];
    const float* w2_1 = (const float*)d_in[9];
    const float* b2_1 = (const float*)d_in[10];
    const float* w2_2 = (const float*)d_in[11];
    const float* b2_2 = (const float*)d_in[12];
    const int* ps = (const int*)d_in[13];
    float* out = (float*)d_out;

    char* ws = (char*)d_ws;
    size_t off = 0;
    auto alloc = [&](size_t bytes) -> void* {
        void* p = ws + off;
        off = (off + bytes + 255) & ~(size_t)255;
        return p;
    };
    u16* wcat = (u16*)alloc(26214400ull * 2);        // [2][5120][2560]
    u16* w21_bf = (u16*)alloc(1638400ull * 2);       // [1280][1280]
    unsigned int* w12p = (unsigned int*)alloc(32768ull * 4);
    u16* xbf = (u16*)alloc(327680ull * 2);           // [256][1280]
    u16* h0a = (u16*)alloc(327680ull * 2);           // [256][1280] (double-buffered)
    u16* h0b = (u16*)alloc(327680ull * 2);
    u16* h1a = (u16*)alloc(327680ull * 2);
    u16* h1b = (u16*)alloc(327680ull * 2);
    float* c0 = (float*)alloc(327680ull * 4);        // [256][1280]
    float* c1 = (float*)alloc(327680ull * 4);
    float* yb = (float*)alloc(327680ull * 4);        // [256][1280]
    float* ins_b = (float*)alloc(5120ull * 4);       // [256][20]

    // weight prep + state init
    cvt_wcat<<<25600, 256, 0, stream>>>(w_ih, w_hh, wcat);
    cvt_kernel<<<1600, 256, 0, stream>>>(w2_1, w21_bf, 1638400);
    cvt_w12p<<<128, 256, 0, stream>>>(w1_2, w12p);
    hipMemsetAsync(c0, 0, 327680ull * 4, stream);
    hipMemsetAsync(c1, 0, 327680ull * 4, stream);
    hipMemsetAsync(h0a, 0, 327680ull * 2, stream);   // h0(-1) = 0
    hipMemsetAsync(h1a, 0, 327680ull * 2, stream);   // h1(-1) = 0

    // t = -1: ins(0) select + MLP1 + MLP2 -> x(0)
    k_out<1><<<256, 256, 0, stream>>>(yb, w2_2, b2_2, inputs, ps, w1_1, b1_1,
                                      w12p, b1_2, out, ins_b, xbf, -1);

    for (int t = 0; t < 63; t++) {
        const u16* h0r = (t & 1) ? h0b : h0a;
        u16*       h0w = (t & 1) ? h0a : h0b;
        const u16* h1r = (t & 1) ? h1b : h1a;
        u16*       h1w = (t & 1) ? h1a : h1b;
        // KA: gates0 = [x(t) | h0(t-1)] @ wcat0^T (K=2560) + cell -> h0(t)
        k_gates<<<160, 256, 0, stream>>>(xbf, h0r, wcat, b_ih, b_hh, c0, h0w);
        // KB: gates1 = [h0(t) | h1(t-1)] @ wcat1^T + cell -> h1(t)
        k_gates<<<160, 256, 0, stream>>>(h0w, h1r, wcat + 13107200,
                                         b_ih + 5120, b_hh + 5120, c1, h1w);
        // KC: y = relu(h1 @ w21^T + b21)
        k_y<<<40, 256, 0, stream>>>(h1w, w21_bf, b2_1, yb);
        // KD: out head + residual + ins(t+1) + MLP1 + MLP2 -> x(t+1)
        k_out<0><<<256, 256, 0, stream>>>(yb, w2_2, b2_2, inputs, ps, w1_1, b1_1,
                                          w12p, b1_2, out, ins_b, xbf, t);
    }
}

// Round 7
// 3708.133 us; speedup vs baseline: 3.4672x; 1.2139x over previous
//
#include <hip/hip_runtime.h>

typedef unsigned short u16;
typedef __bf16 bf16x8 __attribute__((ext_vector_type(8)));
typedef float f32x4 __attribute__((ext_vector_type(4)));

#define AS1 __attribute__((address_space(1)))
#define AS3 __attribute__((address_space(3)))

// B=256, A=5, T=64, NIN=4, NHID=256, L=2, H=1280, 4H=5120, steps=63

__device__ __forceinline__ u16 f2bf(float f) {
    union { float f; unsigned int u; } v; v.f = f;
    unsigned int r = v.u + 0x7fffu + ((v.u >> 16) & 1u);
    return (u16)(r >> 16);
}

__device__ __forceinline__ void ld_lds16(const u16* g, u16* l) {
    __builtin_amdgcn_global_load_lds((AS1 unsigned int*)(unsigned long long)(const void*)g,
                                     (AS3 unsigned int*)l, 16, 0, 0);
}

__device__ __forceinline__ float sigm(float x) { return 1.f / (1.f + __expf(-x)); }
__device__ __forceinline__ float tanh_f(float x) { return 1.f - 2.f / (__expf(2.f * x) + 1.f); }

// ---------------------------------------------------------------------------
// Weight-prep kernels
// ---------------------------------------------------------------------------
__global__ __launch_bounds__(256) void cvt_kernel(const float* __restrict__ src,
                                                  u16* __restrict__ dst, int n) {
    int i = (blockIdx.x * 256 + threadIdx.x) * 4;
    if (i >= n) return;
    float4 v = *(const float4*)(src + i);
    ushort4 o;
    o.x = f2bf(v.x); o.y = f2bf(v.y); o.z = f2bf(v.z); o.w = f2bf(v.w);
    *(ushort4*)(dst + i) = o;
}

// wcat[l][j*4+g][k]: k<1280 -> w_ih[l][g*1280+j][k], else w_hh[..][k-1280]
__global__ __launch_bounds__(256) void cvt_wcat(const float* __restrict__ wih,
                                                const float* __restrict__ whh,
                                                u16* __restrict__ dst) {
    long long idx = ((long long)blockIdx.x * 256 + threadIdx.x) * 4;
    int k = (int)(idx % 2560);
    long long rr = idx / 2560;
    int l = (int)(rr / 5120), r = (int)(rr % 5120);
    int j = r >> 2, g = r & 3;
    long long srow = (long long)l * 5120 + g * 1280 + j;
    const float* s = (k < 1280) ? (wih + srow * 1280 + k) : (whh + srow * 1280 + (k - 1280));
    float4 v = *(const float4*)s;
    ushort4 o;
    o.x = f2bf(v.x); o.y = f2bf(v.y); o.z = f2bf(v.z); o.w = f2bf(v.w);
    *(ushort4*)(dst + idx) = o;
}

__global__ __launch_bounds__(256) void cvt_w12p(const float* __restrict__ w,
                                                unsigned int* __restrict__ dst) {
    int idx = blockIdx.x * 256 + threadIdx.x;  // 32768
    int kk = idx >> 8, j = idx & 255;
    float f0 = w[j * 256 + 2 * kk], f1 = w[j * 256 + 2 * kk + 1];
    dst[idx] = (unsigned)f2bf(f0) | ((unsigned)f2bf(f1) << 16);
}

// ---------------------------------------------------------------------------
// core64: 64x128 tile, K=1280 (20 iters), quad-buffered prefetch (depth 3).
// As: 4 x 4096 u16 (32KB) @0, Bs: 4 x 8192 u16 (64KB) @32768.
// ---------------------------------------------------------------------------
__device__ __forceinline__ void core64(
    const u16* A, int lda, const u16* Bw, int ldb,
    int m0, int n0, u16* As, u16* Bs, f32x4 (&acc)[2][4]) {
    const int nIter = 20;
    int tid = threadIdx.x;
    int w = tid >> 6, l = tid & 63;
    int r8 = l >> 3, g8 = (l & 7) ^ r8;
    const u16* aP = A + (size_t)(m0 + w * 8 + r8) * lda + g8 * 8;
    const u16* bP = Bw + (size_t)(n0 + w * 8 + r8) * ldb + g8 * 8;
    u16* aD = As + w * 512;
    u16* bD = Bs + w * 512;

#define ISSUE64(it)                                            \
    {                                                          \
        int bsel = (it) & 3;                                   \
        const u16* ap = aP + (it) * 64;                        \
        const u16* bp = bP + (it) * 64;                        \
        u16* ad = aD + bsel * 4096;                            \
        u16* bd = bD + bsel * 8192;                            \
        ld_lds16(ap, ad);                                      \
        ld_lds16(ap + (size_t)32 * lda, ad + 2048);            \
        ld_lds16(bp, bd);                                      \
        ld_lds16(bp + (size_t)32 * ldb, bd + 2048);            \
        ld_lds16(bp + (size_t)64 * ldb, bd + 4096);            \
        ld_lds16(bp + (size_t)96 * ldb, bd + 6144);            \
    }

    ISSUE64(0);
    ISSUE64(1);
    ISSUE64(2);
    int wm = w >> 1, wn = w & 1, q = l >> 4, m16 = l & 15;
    for (int it = 0; it < nIter; ++it) {
        if (it + 3 < nIter) ISSUE64(it + 3);
        int ahead = nIter - 1 - it; if (ahead > 3) ahead = 3;
        if (ahead == 3) asm volatile("s_waitcnt vmcnt(18)" ::: "memory");
        else if (ahead == 2) asm volatile("s_waitcnt vmcnt(12)" ::: "memory");
        else if (ahead == 1) asm volatile("s_waitcnt vmcnt(6)" ::: "memory");
        else asm volatile("s_waitcnt vmcnt(0)" ::: "memory");
        asm volatile("s_barrier" ::: "memory");
        const u16* as = As + (it & 3) * 4096;
        const u16* bs = Bs + (it & 3) * 8192;
#pragma unroll
        for (int ks = 0; ks < 2; ks++) {
            bf16x8 af[2], bfr[4];
            int gsw = (ks * 4 + q) ^ (m16 & 7);
#pragma unroll
            for (int i = 0; i < 2; i++) {
                int m = wm * 32 + i * 16 + m16;
                af[i] = *(const bf16x8*)&as[m * 64 + gsw * 8];
            }
#pragma unroll
            for (int j = 0; j < 4; j++) {
                int n = wn * 64 + j * 16 + m16;
                bfr[j] = *(const bf16x8*)&bs[n * 64 + gsw * 8];
            }
#pragma unroll
            for (int i = 0; i < 2; i++)
#pragma unroll
                for (int j = 0; j < 4; j++)
                    acc[i][j] = __builtin_amdgcn_mfma_f32_16x16x32_bf16(af[i], bfr[j], acc[i][j], 0, 0, 0);
        }
        asm volatile("s_barrier" ::: "memory");
    }
#undef ISSUE64
}

// ---------------------------------------------------------------------------
// ghh tile task: GT[col][row] (transposed, [5120][256]) = (Ah @ Bh^T) tile tg.
// tg in 0..159: mb = tg/40 (64-row m block), nb = tg%40 (128-col n block).
// ---------------------------------------------------------------------------
__device__ __forceinline__ void ghh_tile(int tg, const u16* __restrict__ Ah,
                                         const u16* __restrict__ Bh,
                                         float* __restrict__ GT, char* smem) {
    u16* As = (u16*)smem;
    u16* Bs = (u16*)(smem + 32768);
    int mb = tg / 40, nb = tg % 40;
    int m0 = mb * 64, n0 = nb * 128;
    f32x4 acc[2][4];
#pragma unroll
    for (int i = 0; i < 2; i++)
#pragma unroll
        for (int j = 0; j < 4; j++) acc[i][j] = (f32x4){0.f, 0.f, 0.f, 0.f};
    core64(Ah, 1280, Bh, 2560, m0, n0, As, Bs, acc);
    int tid = threadIdx.x;
    int w = tid >> 6, l = tid & 63;
    int wm = w >> 1, wn = w & 1, q = l >> 4, m16 = l & 15;
#pragma unroll
    for (int i = 0; i < 2; i++) {
        int row = m0 + wm * 32 + i * 16 + q * 4;
#pragma unroll
        for (int j = 0; j < 4; j++) {
            int col = n0 + wn * 64 + j * 16 + m16;
            *(f32x4*)&GT[(size_t)col * 256 + row] = acc[i][j];   // 4 rows -> 1 dwordx4
        }
    }
}

// ---------------------------------------------------------------------------
// gates tile task: gates_l tile = (Ag @ Bg^T) + GT_in, fused LSTM cell.
// blk in 0..159. c: per-thread global fp32 RMW. h out bf16 (stride 1280).
// ---------------------------------------------------------------------------
__device__ __forceinline__ void gates_tile(int blk, const u16* __restrict__ Ag,
    const u16* __restrict__ Bg, const float* __restrict__ GT,
    const float* __restrict__ bih, const float* __restrict__ bhh,
    float* __restrict__ cst, u16* __restrict__ hout, char* smem) {
    u16* As = (u16*)smem;
    u16* Bs = (u16*)(smem + 32768);
    float (*cb)[132] = (float(*)[132])smem;   // overlay after core

    int nb = blk % 40, mb = blk / 40;
    int n0 = nb * 128, m0 = mb * 64;

    f32x4 acc[2][4];
#pragma unroll
    for (int i = 0; i < 2; i++)
#pragma unroll
        for (int j = 0; j < 4; j++) acc[i][j] = (f32x4){0.f, 0.f, 0.f, 0.f};

    core64(Ag, 1280, Bg, 2560, m0, n0, As, Bs, acc);

    int tid = threadIdx.x;
    int w = tid >> 6, l = tid & 63;
    int wm = w >> 1, wn = w & 1, q = l >> 4, m16 = l & 15;
#pragma unroll
    for (int i = 0; i < 2; i++)
#pragma unroll
        for (int j = 0; j < 4; j++) {
            int rl = wm * 32 + i * 16 + q * 4;
            int cl = wn * 64 + j * 16 + m16;
            f32x4 gv = *(const f32x4*)&GT[(size_t)(n0 + cl) * 256 + (m0 + rl)];
#pragma unroll
            for (int r = 0; r < 4; r++)
                cb[rl + r][cl] = acc[i][j][r] + gv[r];
        }
    __syncthreads();

    int jt = tid & 31, bt0 = tid >> 5;
    int jg = (n0 >> 2) + jt;
    float bI = bih[jg] + bhh[jg];
    float bF = bih[1280 + jg] + bhh[1280 + jg];
    float bG = bih[2560 + jg] + bhh[2560 + jg];
    float bO = bih[3840 + jg] + bhh[3840 + jg];
#pragma unroll
    for (int p = 0; p < 8; p++) {
        int bt = bt0 + p * 8;
        float4 g4 = *(const float4*)&cb[bt][jt * 4];   // i,f,g,o
        int b = m0 + bt;
        float cv = cst[b * 1280 + jg];
        float cn = sigm(g4.y + bF) * cv + sigm(g4.x + bI) * tanh_f(g4.z + bG);
        cst[b * 1280 + jg] = cn;
        hout[(size_t)b * 1280 + jg] = f2bf(sigm(g4.w + bO) * tanh_f(cn));
    }
}

// ---------------------------------------------------------------------------
// k_gl: 256 blocks. blk<160: gates tiles; blk>=160: ghh tiles 0..95 (A@Bh^T).
// ---------------------------------------------------------------------------
__global__ __launch_bounds__(256) void k_gl(
    const u16* __restrict__ Ag, const u16* __restrict__ Bg,
    const float* __restrict__ GT_in,
    const float* __restrict__ bih, const float* __restrict__ bhh,
    float* __restrict__ cst, u16* __restrict__ hout,
    const u16* __restrict__ Ah, const u16* __restrict__ Bh,
    float* __restrict__ GT_out) {
    __shared__ __align__(16) char smem[98304];
    int blk = blockIdx.x;
    if (blk < 160)
        gates_tile(blk, Ag, Bg, GT_in, bih, bhh, cst, hout, smem);
    else
        ghh_tile(blk - 160, Ah, Bh, GT_out, smem);
}

// ---------------------------------------------------------------------------
// k_c: 168 blocks. blk<40: y = relu(h1@w21^T+b21); blk 40..103: ghh1' tiles
// 96..159 (A=h1); blk 104..167: ghh0' tiles 96..159 (A=h0).
// ---------------------------------------------------------------------------
__global__ __launch_bounds__(256) void k_c(
    const u16* __restrict__ h1, const u16* __restrict__ w21,
    const float* __restrict__ b21, float* __restrict__ yb,
    const u16* __restrict__ h0, const u16* __restrict__ Bh0,
    float* __restrict__ GT0, const u16* __restrict__ Bh1,
    float* __restrict__ GT1) {
    __shared__ __align__(16) char smem[98304];
    int blk = blockIdx.x;
    if (blk < 40) {
        u16* As = (u16*)smem;
        u16* Bs = (u16*)(smem + 32768);
        int nb = blk % 10, mb = blk / 10;
        int n0 = nb * 128, m0 = mb * 64;
        f32x4 acc[2][4];
#pragma unroll
        for (int i = 0; i < 2; i++)
#pragma unroll
            for (int j = 0; j < 4; j++) acc[i][j] = (f32x4){0.f, 0.f, 0.f, 0.f};
        core64(h1, 1280, w21, 1280, m0, n0, As, Bs, acc);
        int tid = threadIdx.x;
        int w = tid >> 6, l = tid & 63;
        int wm = w >> 1, wn = w & 1, q = l >> 4, m16 = l & 15;
#pragma unroll
        for (int i = 0; i < 2; i++) {
            int row = m0 + wm * 32 + i * 16 + q * 4;
#pragma unroll
            for (int j = 0; j < 4; j++) {
                int col = n0 + wn * 64 + j * 16 + m16;
#pragma unroll
                for (int r = 0; r < 4; r++)
                    yb[(size_t)(row + r) * 1280 + col] = fmaxf(acc[i][j][r] + b21[col], 0.f);
            }
        }
    } else if (blk < 104) {
        ghh_tile(96 + (blk - 40), h1, Bh1, GT1, smem);
    } else {
        ghh_tile(96 + (blk - 104), h0, Bh0, GT0, smem);
    }
}

// ---------------------------------------------------------------------------
// k_out: out head (y@w22^T + b22 + ins) -> d_out, teacher-select ins(t+1),
// MLP layer-1, MLP layer-2 -> x(t+1) bf16 [256][1280]. 256 blocks (1/sample).
// ---------------------------------------------------------------------------
template <int FIRST>
__global__ __launch_bounds__(256) void k_out(
    const float* __restrict__ yb, const float* __restrict__ w22,
    const float* __restrict__ b22, const float* __restrict__ inputs,
    const int* __restrict__ ps, const float* __restrict__ w11,
    const float* __restrict__ b11, const unsigned int* __restrict__ w12p,
    const float* __restrict__ b12, float* __restrict__ out,
    float* __restrict__ ins_buf, u16* __restrict__ xnext, int t) {
    __shared__ float ins_s[20];
    __shared__ float act1[5 * 256];
    __shared__ float red[4][20];
    int b = blockIdx.x, tid = threadIdx.x;
    int w = tid >> 6, l = tid & 63;
    int psv = ps[0];

    if (!FIRST) {
        float acc[20];
#pragma unroll
        for (int j = 0; j < 20; j++) acc[j] = 0.f;
        const float* yrow = yb + (size_t)b * 1280;
#pragma unroll
        for (int s = 0; s < 5; s++) {
            int k = w * 320 + s * 64 + l;
            float yv = yrow[k];
#pragma unroll
            for (int j = 0; j < 20; j++) acc[j] = fmaf(yv, w22[j * 1280 + k], acc[j]);
        }
#pragma unroll
        for (int j = 0; j < 20; j++)
#pragma unroll
            for (int off = 32; off; off >>= 1) acc[j] += __shfl_xor(acc[j], off);
        if (l < 20) red[w][l] = acc[l];
        __syncthreads();
        if (tid < 20) {
            float o = red[0][tid] + red[1][tid] + red[2][tid] + red[3][tid]
                      + b22[tid] + ins_buf[b * 20 + tid];
            int a = tid >> 2, n = tid & 3;
            out[(((size_t)b * 5 + a) * 63 + t) * 4 + n] = o;
            float nx = (((t + 1) % psv) == 0)
                           ? inputs[(((size_t)b * 5 + a) * 64 + (t + 1)) * 4 + n] : o;
            ins_s[tid] = nx;
            ins_buf[b * 20 + tid] = nx;
        }
    } else {
        if (tid < 20) {
            int a = tid >> 2, n = tid & 3;
            float nx = inputs[(((size_t)b * 5 + a) * 64) * 4 + n];
            ins_s[tid] = nx;
            ins_buf[b * 20 + tid] = nx;
        }
    }
    __syncthreads();

    int j = tid;
    float4 wv = *(const float4*)(w11 + j * 4);
    float bb = b11[j];
#pragma unroll
    for (int g = 0; g < 5; g++) {
        float v = fmaf(wv.x, ins_s[g * 4],
                  fmaf(wv.y, ins_s[g * 4 + 1],
                  fmaf(wv.z, ins_s[g * 4 + 2],
                  fmaf(wv.w, ins_s[g * 4 + 3], bb))));
        act1[g * 256 + j] = fmaxf(v, 0.f);
    }
    __syncthreads();

    float acc2[5];
    float bb2 = b12[j];
#pragma unroll
    for (int g = 0; g < 5; g++) acc2[g] = bb2;
    for (int kk = 0; kk < 128; kk++) {
        unsigned int pr = w12p[kk * 256 + j];
        union { unsigned int u; float f; } lo, hi;
        lo.u = pr << 16; hi.u = pr & 0xffff0000u;
#pragma unroll
        for (int g = 0; g < 5; g++)
            acc2[g] = fmaf(lo.f, act1[g * 256 + 2 * kk],
                      fmaf(hi.f, act1[g * 256 + 2 * kk + 1], acc2[g]));
    }
#pragma unroll
    for (int g = 0; g < 5; g++)
        xnext[(size_t)b * 1280 + g * 256 + j] = f2bf(fmaxf(acc2[g], 0.f));
}

// ---------------------------------------------------------------------------
extern "C" void kernel_launch(void* const* d_in, const int* in_sizes, int n_in,
                              void* d_out, int out_size, void* d_ws, size_t ws_size,
                              hipStream_t stream) {
    const float* inputs = (const float*)d_in[0];
    const float* w1_1 = (const float*)d_in[1];
    const float* b1_1 = (const float*)d_in[2];
    const float* w1_2 = (const float*)d_in[3];
    const float* b1_2 = (const float*)d_in[4];
    const float* w_ih = (const float*)d_in[5];
    const float* w_hh = (const float*)d_in[6];
    const float* b_ih = (const float*)d_in[7];
    const float* b_hh = (const float*)d_in[8];
    const float* w2_1 = (const float*)d_in[9];
    const float* b2_1 = (const float*)d_in[10];
    const float* w2_2 = (const float*)d_in[11];
    const float* b2_2 = (const float*)d_in[12];
    const int* ps = (const int*)d_in[13];
    float* out = (float*)d_out;

    char* ws = (char*)d_ws;
    size_t off = 0;
    auto alloc = [&](size_t bytes) -> void* {
        void* p = ws + off;
        off = (off + bytes + 255) & ~(size_t)255;
        return p;
    };
    u16* wcat = (u16*)alloc(26214400ull * 2);        // [2][5120][2560]
    u16* w21_bf = (u16*)alloc(1638400ull * 2);       // [1280][1280]
    unsigned int* w12p = (unsigned int*)alloc(32768ull * 4);
    u16* xbf = (u16*)alloc(327680ull * 2);           // [256][1280]
    u16* h0 = (u16*)alloc(327680ull * 2);            // [256][1280]
    u16* h1 = (u16*)alloc(327680ull * 2);            // [256][1280]
    float* c0 = (float*)alloc(327680ull * 4);        // [256][1280]
    float* c1 = (float*)alloc(327680ull * 4);
    float* ghh0T = (float*)alloc(1310720ull * 4);    // [5120][256] transposed
    float* ghh1T = (float*)alloc(1310720ull * 4);    // [5120][256] transposed
    float* yb = (float*)alloc(327680ull * 4);        // [256][1280]
    float* ins_b = (float*)alloc(5120ull * 4);       // [256][20]

    // weight prep + state init
    cvt_wcat<<<25600, 256, 0, stream>>>(w_ih, w_hh, wcat);
    cvt_kernel<<<1600, 256, 0, stream>>>(w2_1, w21_bf, 1638400);
    cvt_w12p<<<128, 256, 0, stream>>>(w1_2, w12p);
    hipMemsetAsync(c0, 0, 327680ull * 4, stream);
    hipMemsetAsync(c1, 0, 327680ull * 4, stream);
    hipMemsetAsync(h1, 0, 327680ull * 2, stream);      // h1(-1) = 0 (read by KA(0) ghh part)
    hipMemsetAsync(ghh0T, 0, 1310720ull * 4, stream);  // h0(-1)=0 -> ghh0(0)=0
    hipMemsetAsync(ghh1T, 0, 1310720ull * 4, stream);  // tiles 96..159 for t=0

    // t = -1: ins(0) select + MLP1 + MLP2 -> x(0)
    k_out<1><<<256, 256, 0, stream>>>(yb, w2_2, b2_2, inputs, ps, w1_1, b1_1,
                                      w12p, b1_2, out, ins_b, xbf, -1);

    const u16* whh0 = wcat + 1280;                     // layer0 hh half
    const u16* wih1 = wcat + 13107200;                 // layer1
    const u16* whh1 = wcat + 13107200 + 1280;          // layer1 hh half

    for (int t = 0; t < 63; t++) {
        // KA: gates0 = x@wih0^T + ghh0T, cell -> h0(t)  ||  ghh1 tiles 0..95 = h1(t-1)@whh1^T
        k_gl<<<256, 256, 0, stream>>>(xbf, wcat, ghh0T, b_ih, b_hh, c0, h0,
                                      h1, whh1, ghh1T);
        // KB: gates1 = h0@wih1^T + ghh1T, cell -> h1(t)  ||  ghh0' tiles 0..95 = h0(t)@whh0^T
        k_gl<<<256, 256, 0, stream>>>(h0, wih1, ghh1T, b_ih + 5120, b_hh + 5120,
                                      c1, h1, h0, whh0, ghh0T);
        // KC: y = relu(h1@w21^T+b21)  ||  ghh1' tiles 96..159 (h1)  ||  ghh0' tiles 96..159 (h0)
        k_c<<<168, 256, 0, stream>>>(h1, w21_bf, b2_1, yb, h0, whh0, ghh0T,
                                     whh1, ghh1T);
        // KD: out head + residual + ins(t+1) + MLP1 + MLP2 -> x(t+1)
        k_out<0><<<256, 256, 0, stream>>>(yb, w2_2, b2_2, inputs, ps, w1_1, b1_1,
                                          w12p, b1_2, out, ins_b, xbf, t);
    }
}

// Round 8
// 3417.096 us; speedup vs baseline: 3.7625x; 1.0852x over previous
//
#include <hip/hip_runtime.h>

typedef unsigned short u16;
typedef __bf16 bf16x8 __attribute__((ext_vector_type(8)));
typedef float f32x4 __attribute__((ext_vector_type(4)));

#define AS1 __attribute__((address_space(1)))
#define AS3 __attribute__((address_space(3)))

// B=256, A=5, T=64, NIN=4, NHID=256, L=2, H=1280, 4H=5120, steps=63

__device__ __forceinline__ u16 f2bf(float f) {
    union { float f; unsigned int u; } v; v.f = f;
    unsigned int r = v.u + 0x7fffu + ((v.u >> 16) & 1u);
    return (u16)(r >> 16);
}

__device__ __forceinline__ void ld_lds16(const u16* g, u16* l) {
    __builtin_amdgcn_global_load_lds((AS1 unsigned int*)(unsigned long long)(const void*)g,
                                     (AS3 unsigned int*)l, 16, 0, 0);
}

__device__ __forceinline__ float sigm(float x) { return 1.f / (1.f + __expf(-x)); }
__device__ __forceinline__ float tanh_f(float x) { return 1.f - 2.f / (__expf(2.f * x) + 1.f); }

// ---------------------------------------------------------------------------
// Weight-prep kernels
// ---------------------------------------------------------------------------
__global__ __launch_bounds__(256) void cvt_kernel(const float* __restrict__ src,
                                                  u16* __restrict__ dst, int n) {
    int i = (blockIdx.x * 256 + threadIdx.x) * 4;
    if (i >= n) return;
    float4 v = *(const float4*)(src + i);
    ushort4 o;
    o.x = f2bf(v.x); o.y = f2bf(v.y); o.z = f2bf(v.z); o.w = f2bf(v.w);
    *(ushort4*)(dst + i) = o;
}

// wcat[l][j*4+g][k]: k<1280 -> w_ih[l][g*1280+j][k], else w_hh[..][k-1280]
__global__ __launch_bounds__(256) void cvt_wcat(const float* __restrict__ wih,
                                                const float* __restrict__ whh,
                                                u16* __restrict__ dst) {
    long long idx = ((long long)blockIdx.x * 256 + threadIdx.x) * 4;
    int k = (int)(idx % 2560);
    long long rr = idx / 2560;
    int l = (int)(rr / 5120), r = (int)(rr % 5120);
    int j = r >> 2, g = r & 3;
    long long srow = (long long)l * 5120 + g * 1280 + j;
    const float* s = (k < 1280) ? (wih + srow * 1280 + k) : (whh + srow * 1280 + (k - 1280));
    float4 v = *(const float4*)s;
    ushort4 o;
    o.x = f2bf(v.x); o.y = f2bf(v.y); o.z = f2bf(v.z); o.w = f2bf(v.w);
    *(ushort4*)(dst + idx) = o;
}

__global__ __launch_bounds__(256) void cvt_w12p(const float* __restrict__ w,
                                                unsigned int* __restrict__ dst) {
    int idx = blockIdx.x * 256 + threadIdx.x;  // 32768
    int kk = idx >> 8, j = idx & 255;
    float f0 = w[j * 256 + 2 * kk], f1 = w[j * 256 + 2 * kk + 1];
    dst[idx] = (unsigned)f2bf(f0) | ((unsigned)f2bf(f1) << 16);
}

// ---------------------------------------------------------------------------
// core64: 64x128 tile, K=1280 (20 iters), quad-buffered prefetch (depth 3),
// 512 threads (8 waves, 2/SIMD). Wave sub-tile 32x32 (acc 2x2).
// Staging: 3 ld_lds16/thread/iter (1 A + 2 B). vmcnt ladder 9/6/3/0.
// As: 4 x 4096 u16 (32KB) @0, Bs: 4 x 8192 u16 (64KB) @32768. 96KB total.
// LDS swizzle invariant: slot s of row r holds k-chunk s^(r&7).
// ---------------------------------------------------------------------------
__device__ __forceinline__ void core64(
    const u16* A, int lda, const u16* Bw, int ldb,
    int m0, int n0, u16* As, u16* Bs, f32x4 (&acc)[2][2]) {
    const int nIter = 20;
    int tid = threadIdx.x;
    int w = tid >> 6, l = tid & 63;
    int r8 = l >> 3, g8 = (l & 7) ^ r8;
    const u16* aP = A + (size_t)(m0 + w * 8 + r8) * lda + g8 * 8;    // A rows w*8..w*8+7
    const u16* bP = Bw + (size_t)(n0 + w * 16 + r8) * ldb + g8 * 8;  // B rows w*16..w*16+15
    u16* aD = As + w * 512;    // 8 rows * 64 u16
    u16* bD = Bs + w * 1024;   // 16 rows * 64 u16

#define ISSUE64(it)                                            \
    {                                                          \
        int bsel = (it) & 3;                                   \
        const u16* ap = aP + (it) * 64;                        \
        const u16* bp = bP + (it) * 64;                        \
        u16* ad = aD + bsel * 4096;                            \
        u16* bd = bD + bsel * 8192;                            \
        ld_lds16(ap, ad);                                      \
        ld_lds16(bp, bd);                                      \
        ld_lds16(bp + (size_t)8 * ldb, bd + 512);              \
    }

    ISSUE64(0);
    ISSUE64(1);
    ISSUE64(2);
    int wm = w >> 2, wn = w & 3, q = l >> 4, m16 = l & 15;
    for (int it = 0; it < nIter; ++it) {
        if (it + 3 < nIter) ISSUE64(it + 3);
        int ahead = nIter - 1 - it; if (ahead > 3) ahead = 3;
        if (ahead == 3) asm volatile("s_waitcnt vmcnt(9)" ::: "memory");
        else if (ahead == 2) asm volatile("s_waitcnt vmcnt(6)" ::: "memory");
        else if (ahead == 1) asm volatile("s_waitcnt vmcnt(3)" ::: "memory");
        else asm volatile("s_waitcnt vmcnt(0)" ::: "memory");
        asm volatile("s_barrier" ::: "memory");
        const u16* as = As + (it & 3) * 4096;
        const u16* bs = Bs + (it & 3) * 8192;
#pragma unroll
        for (int ks = 0; ks < 2; ks++) {
            bf16x8 af[2], bfr[2];
            int gsw = (ks * 4 + q) ^ (m16 & 7);
#pragma unroll
            for (int i = 0; i < 2; i++) {
                int m = wm * 32 + i * 16 + m16;
                af[i] = *(const bf16x8*)&as[m * 64 + gsw * 8];
            }
#pragma unroll
            for (int j = 0; j < 2; j++) {
                int n = wn * 32 + j * 16 + m16;
                bfr[j] = *(const bf16x8*)&bs[n * 64 + gsw * 8];
            }
#pragma unroll
            for (int i = 0; i < 2; i++)
#pragma unroll
                for (int j = 0; j < 2; j++)
                    acc[i][j] = __builtin_amdgcn_mfma_f32_16x16x32_bf16(af[i], bfr[j], acc[i][j], 0, 0, 0);
        }
        asm volatile("s_barrier" ::: "memory");
    }
#undef ISSUE64
}

// ---------------------------------------------------------------------------
// ghh tile task: GT[col][row] (transposed, [5120][256]) = (Ah @ Bh^T) tile tg.
// tg in 0..159: mb = tg/40 (64-row m block), nb = tg%40 (128-col n block).
// ---------------------------------------------------------------------------
__device__ __forceinline__ void ghh_tile(int tg, const u16* __restrict__ Ah,
                                         const u16* __restrict__ Bh,
                                         float* __restrict__ GT, char* smem) {
    u16* As = (u16*)smem;
    u16* Bs = (u16*)(smem + 32768);
    int mb = tg / 40, nb = tg % 40;
    int m0 = mb * 64, n0 = nb * 128;
    f32x4 acc[2][2];
#pragma unroll
    for (int i = 0; i < 2; i++)
#pragma unroll
        for (int j = 0; j < 2; j++) acc[i][j] = (f32x4){0.f, 0.f, 0.f, 0.f};
    core64(Ah, 1280, Bh, 2560, m0, n0, As, Bs, acc);
    int tid = threadIdx.x;
    int w = tid >> 6, l = tid & 63;
    int wm = w >> 2, wn = w & 3, q = l >> 4, m16 = l & 15;
#pragma unroll
    for (int i = 0; i < 2; i++) {
        int row = m0 + wm * 32 + i * 16 + q * 4;
#pragma unroll
        for (int j = 0; j < 2; j++) {
            int col = n0 + wn * 32 + j * 16 + m16;
            *(f32x4*)&GT[(size_t)col * 256 + row] = acc[i][j];   // 4 rows -> 1 dwordx4
        }
    }
}

// ---------------------------------------------------------------------------
// gates tile task: gates_l tile = (Ag @ Bg^T) + GT_in, fused LSTM cell.
// blk in 0..159. c: per-thread global fp32 RMW. h out bf16 (stride 1280).
// ---------------------------------------------------------------------------
__device__ __forceinline__ void gates_tile(int blk, const u16* __restrict__ Ag,
    const u16* __restrict__ Bg, const float* __restrict__ GT,
    const float* __restrict__ bih, const float* __restrict__ bhh,
    float* __restrict__ cst, u16* __restrict__ hout, char* smem) {
    u16* As = (u16*)smem;
    u16* Bs = (u16*)(smem + 32768);
    float (*cb)[132] = (float(*)[132])smem;   // overlay after core

    int nb = blk % 40, mb = blk / 40;
    int n0 = nb * 128, m0 = mb * 64;

    f32x4 acc[2][2];
#pragma unroll
    for (int i = 0; i < 2; i++)
#pragma unroll
        for (int j = 0; j < 2; j++) acc[i][j] = (f32x4){0.f, 0.f, 0.f, 0.f};

    core64(Ag, 1280, Bg, 2560, m0, n0, As, Bs, acc);

    int tid = threadIdx.x;
    int w = tid >> 6, l = tid & 63;
    int wm = w >> 2, wn = w & 3, q = l >> 4, m16 = l & 15;
#pragma unroll
    for (int i = 0; i < 2; i++)
#pragma unroll
        for (int j = 0; j < 2; j++) {
            int rl = wm * 32 + i * 16 + q * 4;
            int cl = wn * 32 + j * 16 + m16;
            f32x4 gv = *(const f32x4*)&GT[(size_t)(n0 + cl) * 256 + (m0 + rl)];
#pragma unroll
            for (int r = 0; r < 4; r++)
                cb[rl + r][cl] = acc[i][j][r] + gv[r];
        }
    __syncthreads();

    int jt = tid & 31, bt0 = tid >> 5;       // jt 0..31, bt0 0..15
    int jg = (n0 >> 2) + jt;
    float bI = bih[jg] + bhh[jg];
    float bF = bih[1280 + jg] + bhh[1280 + jg];
    float bG = bih[2560 + jg] + bhh[2560 + jg];
    float bO = bih[3840 + jg] + bhh[3840 + jg];
#pragma unroll
    for (int p = 0; p < 4; p++) {
        int bt = bt0 + p * 16;
        float4 g4 = *(const float4*)&cb[bt][jt * 4];   // i,f,g,o
        int b = m0 + bt;
        float cv = cst[b * 1280 + jg];
        float cn = sigm(g4.y + bF) * cv + sigm(g4.x + bI) * tanh_f(g4.z + bG);
        cst[b * 1280 + jg] = cn;
        hout[(size_t)b * 1280 + jg] = f2bf(sigm(g4.w + bO) * tanh_f(cn));
    }
}

// ---------------------------------------------------------------------------
// k_gl: 256 blocks x 512 thr. blk<160: gates tiles; blk>=160: ghh tiles 0..95.
// ---------------------------------------------------------------------------
__global__ __launch_bounds__(512) void k_gl(
    const u16* __restrict__ Ag, const u16* __restrict__ Bg,
    const float* __restrict__ GT_in,
    const float* __restrict__ bih, const float* __restrict__ bhh,
    float* __restrict__ cst, u16* __restrict__ hout,
    const u16* __restrict__ Ah, const u16* __restrict__ Bh,
    float* __restrict__ GT_out) {
    __shared__ __align__(16) char smem[98304];
    int blk = blockIdx.x;
    if (blk < 160)
        gates_tile(blk, Ag, Bg, GT_in, bih, bhh, cst, hout, smem);
    else
        ghh_tile(blk - 160, Ah, Bh, GT_out, smem);
}

// ---------------------------------------------------------------------------
// k_c: 168 blocks x 512 thr. blk<40: y = relu(h1@w21^T+b21); blk 40..103:
// ghh1' tiles 96..159 (A=h1); blk 104..167: ghh0' tiles 96..159 (A=h0).
// ---------------------------------------------------------------------------
__global__ __launch_bounds__(512) void k_c(
    const u16* __restrict__ h1, const u16* __restrict__ w21,
    const float* __restrict__ b21, float* __restrict__ yb,
    const u16* __restrict__ h0, const u16* __restrict__ Bh0,
    float* __restrict__ GT0, const u16* __restrict__ Bh1,
    float* __restrict__ GT1) {
    __shared__ __align__(16) char smem[98304];
    int blk = blockIdx.x;
    if (blk < 40) {
        u16* As = (u16*)smem;
        u16* Bs = (u16*)(smem + 32768);
        int nb = blk % 10, mb = blk / 10;
        int n0 = nb * 128, m0 = mb * 64;
        f32x4 acc[2][2];
#pragma unroll
        for (int i = 0; i < 2; i++)
#pragma unroll
            for (int j = 0; j < 2; j++) acc[i][j] = (f32x4){0.f, 0.f, 0.f, 0.f};
        core64(h1, 1280, w21, 1280, m0, n0, As, Bs, acc);
        int tid = threadIdx.x;
        int w = tid >> 6, l = tid & 63;
        int wm = w >> 2, wn = w & 3, q = l >> 4, m16 = l & 15;
#pragma unroll
        for (int i = 0; i < 2; i++) {
            int row = m0 + wm * 32 + i * 16 + q * 4;
#pragma unroll
            for (int j = 0; j < 2; j++) {
                int col = n0 + wn * 32 + j * 16 + m16;
#pragma unroll
                for (int r = 0; r < 4; r++)
                    yb[(size_t)(row + r) * 1280 + col] = fmaxf(acc[i][j][r] + b21[col], 0.f);
            }
        }
    } else if (blk < 104) {
        ghh_tile(96 + (blk - 40), h1, Bh1, GT1, smem);
    } else {
        ghh_tile(96 + (blk - 104), h0, Bh0, GT0, smem);
    }
}

// ---------------------------------------------------------------------------
// k_out: out head (y@w22^T + b22 + ins) -> d_out, teacher-select ins(t+1),
// MLP layer-1, MLP layer-2 -> x(t+1) bf16 [256][1280]. 256 blocks (1/sample).
// ---------------------------------------------------------------------------
template <int FIRST>
__global__ __launch_bounds__(256) void k_out(
    const float* __restrict__ yb, const float* __restrict__ w22,
    const float* __restrict__ b22, const float* __restrict__ inputs,
    const int* __restrict__ ps, const float* __restrict__ w11,
    const float* __restrict__ b11, const unsigned int* __restrict__ w12p,
    const float* __restrict__ b12, float* __restrict__ out,
    float* __restrict__ ins_buf, u16* __restrict__ xnext, int t) {
    __shared__ float ins_s[20];
    __shared__ float act1[5 * 256];
    __shared__ float red[4][20];
    int b = blockIdx.x, tid = threadIdx.x;
    int w = tid >> 6, l = tid & 63;
    int psv = ps[0];

    if (!FIRST) {
        float acc[20];
#pragma unroll
        for (int j = 0; j < 20; j++) acc[j] = 0.f;
        const float* yrow = yb + (size_t)b * 1280;
#pragma unroll
        for (int s = 0; s < 5; s++) {
            int k = w * 320 + s * 64 + l;
            float yv = yrow[k];
#pragma unroll
            for (int j = 0; j < 20; j++) acc[j] = fmaf(yv, w22[j * 1280 + k], acc[j]);
        }
#pragma unroll
        for (int j = 0; j < 20; j++)
#pragma unroll
            for (int off = 32; off; off >>= 1) acc[j] += __shfl_xor(acc[j], off);
        if (l < 20) red[w][l] = acc[l];
        __syncthreads();
        if (tid < 20) {
            float o = red[0][tid] + red[1][tid] + red[2][tid] + red[3][tid]
                      + b22[tid] + ins_buf[b * 20 + tid];
            int a = tid >> 2, n = tid & 3;
            out[(((size_t)b * 5 + a) * 63 + t) * 4 + n] = o;
            float nx = (((t + 1) % psv) == 0)
                           ? inputs[(((size_t)b * 5 + a) * 64 + (t + 1)) * 4 + n] : o;
            ins_s[tid] = nx;
            ins_buf[b * 20 + tid] = nx;
        }
    } else {
        if (tid < 20) {
            int a = tid >> 2, n = tid & 3;
            float nx = inputs[(((size_t)b * 5 + a) * 64) * 4 + n];
            ins_s[tid] = nx;
            ins_buf[b * 20 + tid] = nx;
        }
    }
    __syncthreads();

    int j = tid;
    float4 wv = *(const float4*)(w11 + j * 4);
    float bb = b11[j];
#pragma unroll
    for (int g = 0; g < 5; g++) {
        float v = fmaf(wv.x, ins_s[g * 4],
                  fmaf(wv.y, ins_s[g * 4 + 1],
                  fmaf(wv.z, ins_s[g * 4 + 2],
                  fmaf(wv.w, ins_s[g * 4 + 3], bb))));
        act1[g * 256 + j] = fmaxf(v, 0.f);
    }
    __syncthreads();

    float acc2[5];
    float bb2 = b12[j];
#pragma unroll
    for (int g = 0; g < 5; g++) acc2[g] = bb2;
    for (int kk = 0; kk < 128; kk++) {
        unsigned int pr = w12p[kk * 256 + j];
        union { unsigned int u; float f; } lo, hi;
        lo.u = pr << 16; hi.u = pr & 0xffff0000u;
#pragma unroll
        for (int g = 0; g < 5; g++)
            acc2[g] = fmaf(lo.f, act1[g * 256 + 2 * kk],
                      fmaf(hi.f, act1[g * 256 + 2 * kk + 1], acc2[g]));
    }
#pragma unroll
    for (int g = 0; g < 5; g++)
        xnext[(size_t)b * 1280 + g * 256 + j] = f2bf(fmaxf(acc2[g], 0.f));
}

// ---------------------------------------------------------------------------
extern "C" void kernel_launch(void* const* d_in, const int* in_sizes, int n_in,
                              void* d_out, int out_size, void* d_ws, size_t ws_size,
                              hipStream_t stream) {
    const float* inputs = (const float*)d_in[0];
    const float* w1_1 = (const float*)d_in[1];
    const float* b1_1 = (const float*)d_in[2];
    const float* w1_2 = (const float*)d_in[3];
    const float* b1_2 = (const float*)d_in[4];
    const float* w_ih = (const float*)d_in[5];
    const float* w_hh = (const float*)d_in[6];
    const float* b_ih = (const float*)d_in[7];
    const float* b_hh = (const float*)d_in[8];
    const float* w2_1 = (const float*)d_in[9];
    const float* b2_1 = (const float*)d_in[10];
    const float* w2_2 = (const float*)d_in[11];
    const float* b2_2 = (const float*)d_in[12];
    const int* ps = (const int*)d_in[13];
    float* out = (float*)d_out;

    char* ws = (char*)d_ws;
    size_t off = 0;
    auto alloc = [&](size_t bytes) -> void* {
        void* p = ws + off;
        off = (off + bytes + 255) & ~(size_t)255;
        return p;
    };
    u16* wcat = (u16*)alloc(26214400ull * 2);        // [2][5120][2560]
    u16* w21_bf = (u16*)alloc(1638400ull * 2);       // [1280][1280]
    unsigned int* w12p = (unsigned int*)alloc(32768ull * 4);
    u16* xbf = (u16*)alloc(327680ull * 2);           // [256][1280]
    u16* h0 = (u16*)alloc(327680ull * 2);            // [256][1280]
    u16* h1 = (u16*)alloc(327680ull * 2);            // [256][1280]
    float* c0 = (float*)alloc(327680ull * 4);        // [256][1280]
    float* c1 = (float*)alloc(327680ull * 4);
    float* ghh0T = (float*)alloc(1310720ull * 4);    // [5120][256] transposed
    float* ghh1T = (float*)alloc(1310720ull * 4);    // [5120][256] transposed
    float* yb = (float*)alloc(327680ull * 4);        // [256][1280]
    float* ins_b = (float*)alloc(5120ull * 4);       // [256][20]

    // weight prep + state init
    cvt_wcat<<<25600, 256, 0, stream>>>(w_ih, w_hh, wcat);
    cvt_kernel<<<1600, 256, 0, stream>>>(w2_1, w21_bf, 1638400);
    cvt_w12p<<<128, 256, 0, stream>>>(w1_2, w12p);
    hipMemsetAsync(c0, 0, 327680ull * 4, stream);
    hipMemsetAsync(c1, 0, 327680ull * 4, stream);
    hipMemsetAsync(h1, 0, 327680ull * 2, stream);      // h1(-1) = 0 (read by KA(0) ghh part)
    hipMemsetAsync(ghh0T, 0, 1310720ull * 4, stream);  // h0(-1)=0 -> ghh0(0)=0
    hipMemsetAsync(ghh1T, 0, 1310720ull * 4, stream);  // tiles 96..159 for t=0

    // t = -1: ins(0) select + MLP1 + MLP2 -> x(0)
    k_out<1><<<256, 256, 0, stream>>>(yb, w2_2, b2_2, inputs, ps, w1_1, b1_1,
                                      w12p, b1_2, out, ins_b, xbf, -1);

    const u16* whh0 = wcat + 1280;                     // layer0 hh half
    const u16* wih1 = wcat + 13107200;                 // layer1
    const u16* whh1 = wcat + 13107200 + 1280;          // layer1 hh half

    for (int t = 0; t < 63; t++) {
        // KA: gates0 = x@wih0^T + ghh0T, cell -> h0(t)  ||  ghh1 tiles 0..95 = h1(t-1)@whh1^T
        k_gl<<<256, 512, 0, stream>>>(xbf, wcat, ghh0T, b_ih, b_hh, c0, h0,
                                      h1, whh1, ghh1T);
        // KB: gates1 = h0@wih1^T + ghh1T, cell -> h1(t)  ||  ghh0' tiles 0..95 = h0(t)@whh0^T
        k_gl<<<256, 512, 0, stream>>>(h0, wih1, ghh1T, b_ih + 5120, b_hh + 5120,
                                      c1, h1, h0, whh0, ghh0T);
        // KC: y = relu(h1@w21^T+b21)  ||  ghh1' tiles 96..159 (h1)  ||  ghh0' tiles 96..159 (h0)
        k_c<<<168, 512, 0, stream>>>(h1, w21_bf, b2_1, yb, h0, whh0, ghh0T,
                                     whh1, ghh1T);
        // KD: out head + residual + ins(t+1) + MLP1 + MLP2 -> x(t+1)
        k_out<0><<<256, 256, 0, stream>>>(yb, w2_2, b2_2, inputs, ps, w1_1, b1_1,
                                          w12p, b1_2, out, ins_b, xbf, t);
    }
}

// Round 9
// 3388.961 us; speedup vs baseline: 3.7938x; 1.0083x over previous
//
#include <hip/hip_runtime.h>

typedef unsigned short u16;
typedef __bf16 bf16x8 __attribute__((ext_vector_type(8)));
typedef float f32x4 __attribute__((ext_vector_type(4)));

#define AS1 __attribute__((address_space(1)))
#define AS3 __attribute__((address_space(3)))

// B=256, A=5, T=64, NIN=4, NHID=256, L=2, H=1280, 4H=5120, steps=63

__device__ __forceinline__ u16 f2bf(float f) {
    union { float f; unsigned int u; } v; v.f = f;
    unsigned int r = v.u + 0x7fffu + ((v.u >> 16) & 1u);
    return (u16)(r >> 16);
}

__device__ __forceinline__ void ld_lds16(const u16* g, u16* l) {
    __builtin_amdgcn_global_load_lds((AS1 unsigned int*)(unsigned long long)(const void*)g,
                                     (AS3 unsigned int*)l, 16, 0, 0);
}

__device__ __forceinline__ float sigm(float x) { return 1.f / (1.f + __expf(-x)); }
__device__ __forceinline__ float tanh_f(float x) { return 1.f - 2.f / (__expf(2.f * x) + 1.f); }

// ---------------------------------------------------------------------------
// Weight-prep kernels
// ---------------------------------------------------------------------------
__global__ __launch_bounds__(256) void cvt_kernel(const float* __restrict__ src,
                                                  u16* __restrict__ dst, int n) {
    int i = (blockIdx.x * 256 + threadIdx.x) * 4;
    if (i >= n) return;
    float4 v = *(const float4*)(src + i);
    ushort4 o;
    o.x = f2bf(v.x); o.y = f2bf(v.y); o.z = f2bf(v.z); o.w = f2bf(v.w);
    *(ushort4*)(dst + i) = o;
}

// wcat[l][j*4+g][k]: k<1280 -> w_ih[l][g*1280+j][k], else w_hh[..][k-1280]
__global__ __launch_bounds__(256) void cvt_wcat(const float* __restrict__ wih,
                                                const float* __restrict__ whh,
                                                u16* __restrict__ dst) {
    long long idx = ((long long)blockIdx.x * 256 + threadIdx.x) * 4;
    int k = (int)(idx % 2560);
    long long rr = idx / 2560;
    int l = (int)(rr / 5120), r = (int)(rr % 5120);
    int j = r >> 2, g = r & 3;
    long long srow = (long long)l * 5120 + g * 1280 + j;
    const float* s = (k < 1280) ? (wih + srow * 1280 + k) : (whh + srow * 1280 + (k - 1280));
    float4 v = *(const float4*)s;
    ushort4 o;
    o.x = f2bf(v.x); o.y = f2bf(v.y); o.z = f2bf(v.z); o.w = f2bf(v.w);
    *(ushort4*)(dst + idx) = o;
}

__global__ __launch_bounds__(256) void cvt_w12p(const float* __restrict__ w,
                                                unsigned int* __restrict__ dst) {
    int idx = blockIdx.x * 256 + threadIdx.x;  // 32768
    int kk = idx >> 8, j = idx & 255;
    float f0 = w[j * 256 + 2 * kk], f1 = w[j * 256 + 2 * kk + 1];
    dst[idx] = (unsigned)f2bf(f0) | ((unsigned)f2bf(f1) << 16);
}

// ---------------------------------------------------------------------------
// core64: 64x128 tile, K=1280 as 10 iters of BK=128, triple-buffered
// (prefetch depth 2), 512 threads (8 waves, 2/SIMD). Wave sub-tile 32x32.
// LDS rows are 128 u16 (256B), 16 chunks of 16B; swizzle: chunk c of row r
// stored at slot c^(r&15). Staging: 6 ld_lds16/thread/iter (2 A + 4 B).
// As: 3 x 8192 u16 (16KB) @0; Bs: 3 x 16384 u16 (32KB) @49152. 144KB total.
// vmcnt ladder 12/6/0.
// ---------------------------------------------------------------------------
__device__ __forceinline__ void core64(
    const u16* A, int lda, const u16* Bw, int ldb,
    int m0, int n0, u16* As, u16* Bs, f32x4 (&acc)[2][2]) {
    const int nIter = 10;
    int tid = threadIdx.x;
    int w = tid >> 6, l = tid & 63;
    int r4 = l >> 4;       // row within 4-row instr group
    int c16 = l & 15;      // chunk 0..15

    // A: wave w covers tile rows w*8 + s*4 + r4 (s=0..1)
    int aR0 = w * 8 + r4, aR1 = w * 8 + 4 + r4;
    const u16* aP0 = A + (size_t)(m0 + aR0) * lda + (c16 ^ (aR0 & 15)) * 8;
    const u16* aP1 = A + (size_t)(m0 + aR1) * lda + (c16 ^ (aR1 & 15)) * 8;
    // B: wave w covers tile rows w*16 + s*4 + r4 (s=0..3)
    int bR0 = w * 16 + r4, bR1 = bR0 + 4, bR2 = bR0 + 8, bR3 = bR0 + 12;
    const u16* bP0 = Bw + (size_t)(n0 + bR0) * ldb + (c16 ^ (bR0 & 15)) * 8;
    const u16* bP1 = Bw + (size_t)(n0 + bR1) * ldb + (c16 ^ (bR1 & 15)) * 8;
    const u16* bP2 = Bw + (size_t)(n0 + bR2) * ldb + (c16 ^ (bR2 & 15)) * 8;
    const u16* bP3 = Bw + (size_t)(n0 + bR3) * ldb + (c16 ^ (bR3 & 15)) * 8;
    u16* aD = As + w * 1024;   // 8 rows * 128 u16
    u16* bD = Bs + w * 2048;   // 16 rows * 128 u16

#define ISSUE64(it)                                            \
    {                                                          \
        int bsel = (it) % 3;                                   \
        int ko = (it) * 128;                                   \
        u16* ad = aD + bsel * 8192;                            \
        u16* bd = bD + bsel * 16384;                           \
        ld_lds16(aP0 + ko, ad);                                \
        ld_lds16(aP1 + ko, ad + 512);                          \
        ld_lds16(bP0 + ko, bd);                                \
        ld_lds16(bP1 + ko, bd + 512);                          \
        ld_lds16(bP2 + ko, bd + 1024);                         \
        ld_lds16(bP3 + ko, bd + 1536);                         \
    }

    ISSUE64(0);
    ISSUE64(1);
    int wm = w >> 2, wn = w & 3, q = l >> 4, m16 = l & 15;
    for (int it = 0; it < nIter; ++it) {
        if (it + 2 < nIter) ISSUE64(it + 2);
        int ahead = nIter - 1 - it; if (ahead > 2) ahead = 2;
        if (ahead == 2) asm volatile("s_waitcnt vmcnt(12)" ::: "memory");
        else if (ahead == 1) asm volatile("s_waitcnt vmcnt(6)" ::: "memory");
        else asm volatile("s_waitcnt vmcnt(0)" ::: "memory");
        asm volatile("s_barrier" ::: "memory");
        const u16* as = As + (it % 3) * 8192;
        const u16* bs = Bs + (it % 3) * 16384;
#pragma unroll
        for (int ks = 0; ks < 4; ks++) {
            bf16x8 af[2], bfr[2];
            int gsw = (ks * 4 + q) ^ m16;
#pragma unroll
            for (int i = 0; i < 2; i++) {
                int m = wm * 32 + i * 16 + m16;
                af[i] = *(const bf16x8*)&as[m * 128 + gsw * 8];
            }
#pragma unroll
            for (int j = 0; j < 2; j++) {
                int n = wn * 32 + j * 16 + m16;
                bfr[j] = *(const bf16x8*)&bs[n * 128 + gsw * 8];
            }
#pragma unroll
            for (int i = 0; i < 2; i++)
#pragma unroll
                for (int j = 0; j < 2; j++)
                    acc[i][j] = __builtin_amdgcn_mfma_f32_16x16x32_bf16(af[i], bfr[j], acc[i][j], 0, 0, 0);
        }
        asm volatile("s_barrier" ::: "memory");
    }
#undef ISSUE64
}

// ---------------------------------------------------------------------------
// ghh tile task: GT[col][row] (transposed, [5120][256]) = (Ah @ Bh^T) tile tg.
// tg in 0..159: mb = tg/40 (64-row m block), nb = tg%40 (128-col n block).
// ---------------------------------------------------------------------------
__device__ __forceinline__ void ghh_tile(int tg, const u16* __restrict__ Ah,
                                         const u16* __restrict__ Bh,
                                         float* __restrict__ GT, char* smem) {
    u16* As = (u16*)smem;
    u16* Bs = (u16*)(smem + 49152);
    int mb = tg / 40, nb = tg % 40;
    int m0 = mb * 64, n0 = nb * 128;
    f32x4 acc[2][2];
#pragma unroll
    for (int i = 0; i < 2; i++)
#pragma unroll
        for (int j = 0; j < 2; j++) acc[i][j] = (f32x4){0.f, 0.f, 0.f, 0.f};
    core64(Ah, 1280, Bh, 2560, m0, n0, As, Bs, acc);
    int tid = threadIdx.x;
    int w = tid >> 6, l = tid & 63;
    int wm = w >> 2, wn = w & 3, q = l >> 4, m16 = l & 15;
#pragma unroll
    for (int i = 0; i < 2; i++) {
        int row = m0 + wm * 32 + i * 16 + q * 4;
#pragma unroll
        for (int j = 0; j < 2; j++) {
            int col = n0 + wn * 32 + j * 16 + m16;
            *(f32x4*)&GT[(size_t)col * 256 + row] = acc[i][j];   // 4 rows -> 1 dwordx4
        }
    }
}

// ---------------------------------------------------------------------------
// gates tile task: gates_l tile = (Ag @ Bg^T) + GT_in, fused LSTM cell.
// blk in 0..159. c: per-thread global fp32 RMW. h out bf16 (stride 1280).
// ---------------------------------------------------------------------------
__device__ __forceinline__ void gates_tile(int blk, const u16* __restrict__ Ag,
    const u16* __restrict__ Bg, const float* __restrict__ GT,
    const float* __restrict__ bih, const float* __restrict__ bhh,
    float* __restrict__ cst, u16* __restrict__ hout, char* smem) {
    u16* As = (u16*)smem;
    u16* Bs = (u16*)(smem + 49152);
    float (*cb)[132] = (float(*)[132])smem;   // overlay after core

    int nb = blk % 40, mb = blk / 40;
    int n0 = nb * 128, m0 = mb * 64;

    f32x4 acc[2][2];
#pragma unroll
    for (int i = 0; i < 2; i++)
#pragma unroll
        for (int j = 0; j < 2; j++) acc[i][j] = (f32x4){0.f, 0.f, 0.f, 0.f};

    core64(Ag, 1280, Bg, 2560, m0, n0, As, Bs, acc);

    int tid = threadIdx.x;
    int w = tid >> 6, l = tid & 63;
    int wm = w >> 2, wn = w & 3, q = l >> 4, m16 = l & 15;
#pragma unroll
    for (int i = 0; i < 2; i++)
#pragma unroll
        for (int j = 0; j < 2; j++) {
            int rl = wm * 32 + i * 16 + q * 4;
            int cl = wn * 32 + j * 16 + m16;
            f32x4 gv = *(const f32x4*)&GT[(size_t)(n0 + cl) * 256 + (m0 + rl)];
#pragma unroll
            for (int r = 0; r < 4; r++)
                cb[rl + r][cl] = acc[i][j][r] + gv[r];
        }
    __syncthreads();

    int jt = tid & 31, bt0 = tid >> 5;       // jt 0..31, bt0 0..15
    int jg = (n0 >> 2) + jt;
    float bI = bih[jg] + bhh[jg];
    float bF = bih[1280 + jg] + bhh[1280 + jg];
    float bG = bih[2560 + jg] + bhh[2560 + jg];
    float bO = bih[3840 + jg] + bhh[3840 + jg];
#pragma unroll
    for (int p = 0; p < 4; p++) {
        int bt = bt0 + p * 16;
        float4 g4 = *(const float4*)&cb[bt][jt * 4];   // i,f,g,o
        int b = m0 + bt;
        float cv = cst[b * 1280 + jg];
        float cn = sigm(g4.y + bF) * cv + sigm(g4.x + bI) * tanh_f(g4.z + bG);
        cst[b * 1280 + jg] = cn;
        hout[(size_t)b * 1280 + jg] = f2bf(sigm(g4.w + bO) * tanh_f(cn));
    }
}

// ---------------------------------------------------------------------------
// k_gl: 256 blocks x 512 thr. blk<160: gates tiles; blk>=160: ghh tiles 0..95.
// ---------------------------------------------------------------------------
__global__ __launch_bounds__(512) void k_gl(
    const u16* __restrict__ Ag, const u16* __restrict__ Bg,
    const float* __restrict__ GT_in,
    const float* __restrict__ bih, const float* __restrict__ bhh,
    float* __restrict__ cst, u16* __restrict__ hout,
    const u16* __restrict__ Ah, const u16* __restrict__ Bh,
    float* __restrict__ GT_out) {
    __shared__ __align__(16) char smem[147456];
    int blk = blockIdx.x;
    if (blk < 160)
        gates_tile(blk, Ag, Bg, GT_in, bih, bhh, cst, hout, smem);
    else
        ghh_tile(blk - 160, Ah, Bh, GT_out, smem);
}

// ---------------------------------------------------------------------------
// k_c: 168 blocks x 512 thr. blk<40: y = relu(h1@w21^T+b21); blk 40..103:
// ghh1' tiles 96..159 (A=h1); blk 104..167: ghh0' tiles 96..159 (A=h0).
// ---------------------------------------------------------------------------
__global__ __launch_bounds__(512) void k_c(
    const u16* __restrict__ h1, const u16* __restrict__ w21,
    const float* __restrict__ b21, float* __restrict__ yb,
    const u16* __restrict__ h0, const u16* __restrict__ Bh0,
    float* __restrict__ GT0, const u16* __restrict__ Bh1,
    float* __restrict__ GT1) {
    __shared__ __align__(16) char smem[147456];
    int blk = blockIdx.x;
    if (blk < 40) {
        u16* As = (u16*)smem;
        u16* Bs = (u16*)(smem + 49152);
        int nb = blk % 10, mb = blk / 10;
        int n0 = nb * 128, m0 = mb * 64;
        f32x4 acc[2][2];
#pragma unroll
        for (int i = 0; i < 2; i++)
#pragma unroll
            for (int j = 0; j < 2; j++) acc[i][j] = (f32x4){0.f, 0.f, 0.f, 0.f};
        core64(h1, 1280, w21, 1280, m0, n0, As, Bs, acc);
        int tid = threadIdx.x;
        int w = tid >> 6, l = tid & 63;
        int wm = w >> 2, wn = w & 3, q = l >> 4, m16 = l & 15;
#pragma unroll
        for (int i = 0; i < 2; i++) {
            int row = m0 + wm * 32 + i * 16 + q * 4;
#pragma unroll
            for (int j = 0; j < 2; j++) {
                int col = n0 + wn * 32 + j * 16 + m16;
#pragma unroll
                for (int r = 0; r < 4; r++)
                    yb[(size_t)(row + r) * 1280 + col] = fmaxf(acc[i][j][r] + b21[col], 0.f);
            }
        }
    } else if (blk < 104) {
        ghh_tile(96 + (blk - 40), h1, Bh1, GT1, smem);
    } else {
        ghh_tile(96 + (blk - 104), h0, Bh0, GT0, smem);
    }
}

// ---------------------------------------------------------------------------
// k_out: out head (y@w22^T + b22 + ins) -> d_out, teacher-select ins(t+1),
// MLP layer-1, MLP layer-2 -> x(t+1) bf16 [256][1280]. 256 blocks (1/sample).
// ---------------------------------------------------------------------------
template <int FIRST>
__global__ __launch_bounds__(256) void k_out(
    const float* __restrict__ yb, const float* __restrict__ w22,
    const float* __restrict__ b22, const float* __restrict__ inputs,
    const int* __restrict__ ps, const float* __restrict__ w11,
    const float* __restrict__ b11, const unsigned int* __restrict__ w12p,
    const float* __restrict__ b12, float* __restrict__ out,
    float* __restrict__ ins_buf, u16* __restrict__ xnext, int t) {
    __shared__ float ins_s[20];
    __shared__ float act1[5 * 256];
    __shared__ float red[4][20];
    int b = blockIdx.x, tid = threadIdx.x;
    int w = tid >> 6, l = tid & 63;
    int psv = ps[0];

    if (!FIRST) {
        float acc[20];
#pragma unroll
        for (int j = 0; j < 20; j++) acc[j] = 0.f;
        const float* yrow = yb + (size_t)b * 1280;
#pragma unroll
        for (int s = 0; s < 5; s++) {
            int k = w * 320 + s * 64 + l;
            float yv = yrow[k];
#pragma unroll
            for (int j = 0; j < 20; j++) acc[j] = fmaf(yv, w22[j * 1280 + k], acc[j]);
        }
#pragma unroll
        for (int j = 0; j < 20; j++)
#pragma unroll
            for (int off = 32; off; off >>= 1) acc[j] += __shfl_xor(acc[j], off);
        if (l < 20) red[w][l] = acc[l];
        __syncthreads();
        if (tid < 20) {
            float o = red[0][tid] + red[1][tid] + red[2][tid] + red[3][tid]
                      + b22[tid] + ins_buf[b * 20 + tid];
            int a = tid >> 2, n = tid & 3;
            out[(((size_t)b * 5 + a) * 63 + t) * 4 + n] = o;
            float nx = (((t + 1) % psv) == 0)
                           ? inputs[(((size_t)b * 5 + a) * 64 + (t + 1)) * 4 + n] : o;
            ins_s[tid] = nx;
            ins_buf[b * 20 + tid] = nx;
        }
    } else {
        if (tid < 20) {
            int a = tid >> 2, n = tid & 3;
            float nx = inputs[(((size_t)b * 5 + a) * 64) * 4 + n];
            ins_s[tid] = nx;
            ins_buf[b * 20 + tid] = nx;
        }
    }
    __syncthreads();

    int j = tid;
    float4 wv = *(const float4*)(w11 + j * 4);
    float bb = b11[j];
#pragma unroll
    for (int g = 0; g < 5; g++) {
        float v = fmaf(wv.x, ins_s[g * 4],
                  fmaf(wv.y, ins_s[g * 4 + 1],
                  fmaf(wv.z, ins_s[g * 4 + 2],
                  fmaf(wv.w, ins_s[g * 4 + 3], bb))));
        act1[g * 256 + j] = fmaxf(v, 0.f);
    }
    __syncthreads();

    float acc2[5];
    float bb2 = b12[j];
#pragma unroll
    for (int g = 0; g < 5; g++) acc2[g] = bb2;
    for (int kk = 0; kk < 128; kk++) {
        unsigned int pr = w12p[kk * 256 + j];
        union { unsigned int u; float f; } lo, hi;
        lo.u = pr << 16; hi.u = pr & 0xffff0000u;
#pragma unroll
        for (int g = 0; g < 5; g++)
            acc2[g] = fmaf(lo.f, act1[g * 256 + 2 * kk],
                      fmaf(hi.f, act1[g * 256 + 2 * kk + 1], acc2[g]));
    }
#pragma unroll
    for (int g = 0; g < 5; g++)
        xnext[(size_t)b * 1280 + g * 256 + j] = f2bf(fmaxf(acc2[g], 0.f));
}

// ---------------------------------------------------------------------------
extern "C" void kernel_launch(void* const* d_in, const int* in_sizes, int n_in,
                              void* d_out, int out_size, void* d_ws, size_t ws_size,
                              hipStream_t stream) {
    const float* inputs = (const float*)d_in[0];
    const float* w1_1 = (const float*)d_in[1];
    const float* b1_1 = (const float*)d_in[2];
    const float* w1_2 = (const float*)d_in[3];
    const float* b1_2 = (const float*)d_in[4];
    const float* w_ih = (const float*)d_in[5];
    const float* w_hh = (const float*)d_in[6];
    const float* b_ih = (const float*)d_in[7];
    const float* b_hh = (const float*)d_in[8];
    const float* w2_1 = (const float*)d_in[9];
    const float* b2_1 = (const float*)d_in[10];
    const float* w2_2 = (const float*)d_in[11];
    const float* b2_2 = (const float*)d_in[12];
    const int* ps = (const int*)d_in[13];
    float* out = (float*)d_out;

    char* ws = (char*)d_ws;
    size_t off = 0;
    auto alloc = [&](size_t bytes) -> void* {
        void* p = ws + off;
        off = (off + bytes + 255) & ~(size_t)255;
        return p;
    };
    u16* wcat = (u16*)alloc(26214400ull * 2);        // [2][5120][2560]
    u16* w21_bf = (u16*)alloc(1638400ull * 2);       // [1280][1280]
    unsigned int* w12p = (unsigned int*)alloc(32768ull * 4);
    u16* xbf = (u16*)alloc(327680ull * 2);           // [256][1280]
    u16* h0 = (u16*)alloc(327680ull * 2);            // [256][1280]
    u16* h1 = (u16*)alloc(327680ull * 2);            // [256][1280]
    float* c0 = (float*)alloc(327680ull * 4);        // [256][1280]
    float* c1 = (float*)alloc(327680ull * 4);
    float* ghh0T = (float*)alloc(1310720ull * 4);    // [5120][256] transposed
    float* ghh1T = (float*)alloc(1310720ull * 4);    // [5120][256] transposed
    float* yb = (float*)alloc(327680ull * 4);        // [256][1280]
    float* ins_b = (float*)alloc(5120ull * 4);       // [256][20]

    // weight prep + state init
    cvt_wcat<<<25600, 256, 0, stream>>>(w_ih, w_hh, wcat);
    cvt_kernel<<<1600, 256, 0, stream>>>(w2_1, w21_bf, 1638400);
    cvt_w12p<<<128, 256, 0, stream>>>(w1_2, w12p);
    hipMemsetAsync(c0, 0, 327680ull * 4, stream);
    hipMemsetAsync(c1, 0, 327680ull * 4, stream);
    hipMemsetAsync(h1, 0, 327680ull * 2, stream);      // h1(-1) = 0 (read by KA(0) ghh part)
    hipMemsetAsync(ghh0T, 0, 1310720ull * 4, stream);  // h0(-1)=0 -> ghh0(0)=0
    hipMemsetAsync(ghh1T, 0, 1310720ull * 4, stream);  // tiles 96..159 for t=0

    // t = -1: ins(0) select + MLP1 + MLP2 -> x(0)
    k_out<1><<<256, 256, 0, stream>>>(yb, w2_2, b2_2, inputs, ps, w1_1, b1_1,
                                      w12p, b1_2, out, ins_b, xbf, -1);

    const u16* whh0 = wcat + 1280;                     // layer0 hh half
    const u16* wih1 = wcat + 13107200;                 // layer1
    const u16* whh1 = wcat + 13107200 + 1280;          // layer1 hh half

    for (int t = 0; t < 63; t++) {
        // KA: gates0 = x@wih0^T + ghh0T, cell -> h0(t)  ||  ghh1 tiles 0..95 = h1(t-1)@whh1^T
        k_gl<<<256, 512, 0, stream>>>(xbf, wcat, ghh0T, b_ih, b_hh, c0, h0,
                                      h1, whh1, ghh1T);
        // KB: gates1 = h0@wih1^T + ghh1T, cell -> h1(t)  ||  ghh0' tiles 0..95 = h0(t)@whh0^T
        k_gl<<<256, 512, 0, stream>>>(h0, wih1, ghh1T, b_ih + 5120, b_hh + 5120,
                                      c1, h1, h0, whh0, ghh0T);
        // KC: y = relu(h1@w21^T+b21)  ||  ghh1' tiles 96..159 (h1)  ||  ghh0' tiles 96..159 (h0)
        k_c<<<168, 512, 0, stream>>>(h1, w21_bf, b2_1, yb, h0, whh0, ghh0T,
                                     whh1, ghh1T);
        // KD: out head + residual + ins(t+1) + MLP1 + MLP2 -> x(t+1)
        k_out<0><<<256, 256, 0, stream>>>(yb, w2_2, b2_2, inputs, ps, w1_1, b1_1,
                                          w12p, b1_2, out, ins_b, xbf, t);
    }
}